// Round 7
// baseline (506.487 us; speedup 1.0000x reference)
//
#include <hip/hip_runtime.h>
#include <cstdint>

#define NH 8
#define HD 96
#define CDIM 768
#define BQ 2
#define T0 8
#define H0 56
#define W0 56
#define L0 (T0*H0*W0)     // 25088
#define HP_Q 28
#define WP_Q 28
#define LQ (T0*HP_Q*WP_Q) // 6272
#define HP_K 7
#define WP_K 7
#define LK (T0*HP_K*WP_K) // 392
#define LKP 416           // kv padded to multiple of 32
#define SCALE 0.10206207261596577f

typedef __bf16 bf16;
typedef bf16 bf16x4 __attribute__((ext_vector_type(4)));
typedef bf16 bf16x8 __attribute__((ext_vector_type(8)));
typedef float f32x4 __attribute__((ext_vector_type(4)));
typedef float f4 __attribute__((ext_vector_type(4)));

#define GPTR(x) ((const __attribute__((address_space(1))) void*)(x))
#define LPTR(x) ((__attribute__((address_space(3))) void*)(x))

// fast erf-GELU: A&S 7.1.27 rational erf approx, |err(erf)| <= 5e-4 (<< bf16 rounding)
__device__ __forceinline__ float fast_gelu(float x) {
    float z = __builtin_fabsf(x) * 0.7071067811865476f;
    float p = 1.f + z*(0.278393f + z*(0.230389f + z*(0.000972f + z*0.078108f)));
    p = p * p;
    p = p * p;
    float e = 1.f - __builtin_amdgcn_rcpf(p);   // erf(|x|/sqrt2)
    float erfv = (x < 0.f) ? -e : e;
    return 0.5f * x * (1.f + erfv);
}

// ---------------- fp32 -> bf16 conversion ----------------
__global__ void cvt4(const f4* __restrict__ in, bf16x4* __restrict__ out, long n4) {
    long i = (long)blockIdx.x * blockDim.x + threadIdx.x;
    long stride = (long)gridDim.x * blockDim.x;
    for (; i < n4; i += stride) {
        f4 v = in[i];
        bf16x4 o;
        o.x = (bf16)v.x; o.y = (bf16)v.y; o.z = (bf16)v.z; o.w = (bf16)v.w;
        out[i] = o;
    }
}

// ============ 256x256 8-wave 4-phase qkv GEMM (T1+T2+T3/T4+T5) ============
// out = A[50176x768] @ B^T[2304x768] + bias; GELU on cols<768 (Q part);
// scatter bf16 to [part][b*NH+nh][L0][HD].
// Race-free schedule: tile t+1's prefetch issued only AFTER tile-t boundary
// barrier (its dest buffer was last read at tile t-1, finished by all waves);
// one vmcnt(0)+raw-barrier per K-tile (loads were issued a full tile earlier).
__global__ __launch_bounds__(512, 2) void gemm256_qkv(
    const bf16* __restrict__ A, const bf16* __restrict__ B,
    const float* __restrict__ bias, bf16* __restrict__ Out, int K, int NBN)
{
    __shared__ bf16 sh[2*32768];     // 2 bufs x (A 16384 | B 16384) elems = 128 KiB
    const int tid = threadIdx.x;
    const int lane = tid & 63;
    const int wid = tid >> 6;
    const int wm = wid >> 2, wn = wid & 3;   // 2(M) x 4(N) wave grid

    // T1: XCD-chunked bijective swizzle (m204)
    const int nwg = gridDim.x;
    const int q_ = nwg >> 3, r_ = nwg & 7;
    const int xcd = blockIdx.x & 7, off = blockIdx.x >> 3;
    const int swz = (xcd < r_ ? xcd*(q_+1) : r_*(q_+1) + (xcd - r_)*q_) + off;
    const long bn = swz % NBN, bm = swz / NBN;

    f32x4 acc[8][4];
#pragma unroll
    for (int i = 0; i < 8; ++i)
#pragma unroll
        for (int j = 0; j < 4; ++j) acc[i][j] = (f32x4){0.f,0.f,0.f,0.f};

    const int arow = lane & 15;
    const int g = lane >> 4;          // 0..3
    const int srow = tid >> 3;        // 0..63
    const int schunk = tid & 7;

    const bf16* Abase = A + (bm*256 + srow)*(long)K;
    const bf16* Bbase = B + (bn*256 + srow)*(long)K;

    // stage one 64-row slab (8KB) of A or B for K-tile kt into buf
    auto stageA = [&](int buf, int kt, int s) {
        int row = s*64 + srow;
        int c = schunk ^ (row & 7);                 // inverse swizzle on SOURCE
        __builtin_amdgcn_global_load_lds(
            GPTR(Abase + (long)s*64*K + kt*64 + c*8),
            LPTR(sh + buf*32768 + row*64 + schunk*8), 16, 0, 0);
    };
    auto stageB = [&](int buf, int kt, int s) {
        int row = s*64 + srow;
        int c = schunk ^ (row & 7);
        __builtin_amdgcn_global_load_lds(
            GPTR(Bbase + (long)s*64*K + kt*64 + c*8),
            LPTR(sh + buf*32768 + 16384 + row*64 + schunk*8), 16, 0, 0);
    };

    const int nkt = K / 64;
    // prologue: stage tile 0 into buf 0
#pragma unroll
    for (int s = 0; s < 4; ++s) { stageA(0, 0, s); stageB(0, 0, s); }

    for (int kt = 0; kt < nkt; ++kt) {
        const int cur = kt & 1, nxt = cur ^ 1;
        asm volatile("s_waitcnt vmcnt(0)" ::: "memory");
        __builtin_amdgcn_s_barrier();
        const bool pre = (kt + 1 < nkt);
#pragma unroll
        for (int p = 0; p < 4; ++p) {
            // prefetch next tile, spread over phases (dest=nxt, free since t-1)
            if (pre) {
                if (p == 0) { stageA(nxt, kt+1, 0); stageB(nxt, kt+1, 0);
                              stageA(nxt, kt+1, 1); stageB(nxt, kt+1, 1); }
                else if (p == 1) { stageA(nxt, kt+1, 2); stageB(nxt, kt+1, 2); }
                else if (p == 2) { stageA(nxt, kt+1, 3); stageB(nxt, kt+1, 3); }
            }
            const int qm = p >> 1, qn = p & 1;      // C-quadrant
            const bf16* ldsA = sh + cur*32768;
            const bf16* ldsB = sh + cur*32768 + 16384;
            bf16x8 af[4][2], bfr[2][2];
#pragma unroll
            for (int i = 0; i < 4; ++i) {
                int row = wm*128 + (qm*4 + i)*16 + arow;
#pragma unroll
                for (int kk = 0; kk < 2; ++kk)
                    af[i][kk] = *(const bf16x8*)&ldsA[row*64 + (((kk*4 + g) ^ (row & 7))*8)];
            }
#pragma unroll
            for (int j = 0; j < 2; ++j) {
                int row = wn*64 + (qn*2 + j)*16 + arow;
#pragma unroll
                for (int kk = 0; kk < 2; ++kk)
                    bfr[j][kk] = *(const bf16x8*)&ldsB[row*64 + (((kk*4 + g) ^ (row & 7))*8)];
            }
            __builtin_amdgcn_s_setprio(1);
#pragma unroll
            for (int i = 0; i < 4; ++i)
#pragma unroll
                for (int j = 0; j < 2; ++j)
#pragma unroll
                    for (int kk = 0; kk < 2; ++kk)
                        acc[qm*4 + i][qn*2 + j] = __builtin_amdgcn_mfma_f32_16x16x32_bf16(
                            af[i][kk], bfr[j][kk], acc[qm*4 + i][qn*2 + j], 0, 0, 0);
            __builtin_amdgcn_s_setprio(0);
            __builtin_amdgcn_sched_barrier(0);
        }
    }

    // ---------------- epilogue: LDS transpose in 2 M-halves, bf16x8 stores -------
    bf16* tls = sh;                   // 128 x 264 bf16 = 67.5 KB
    const bool do_gelu = (bn < 3);    // part 0 = Q
#pragma unroll 1
    for (int half = 0; half < 2; ++half) {
        __syncthreads();
        if (wm == half) {
#pragma unroll
            for (int mf = 0; mf < 8; ++mf) {
                int rowl = mf*16 + (g << 2);
#pragma unroll
                for (int nf = 0; nf < 4; ++nf) {
                    int coll = wn*64 + nf*16 + arow;
                    float bcol = bias[bn*256 + coll];
#pragma unroll
                    for (int r = 0; r < 4; ++r) {
                        float v = acc[mf][nf][r] + bcol;
                        if (do_gelu) v = fast_gelu(v);
                        tls[(rowl + r)*264 + coll] = (bf16)v;
                    }
                }
            }
        }
        __syncthreads();
#pragma unroll
        for (int it = 0; it < 8; ++it) {
            int idx = it*512 + tid;           // 0..4095
            int mloc = idx >> 5;              // 0..127
            int ck = idx & 31;                // 16B chunk within 256 cols
            bf16x8 v = *(const bf16x8*)&tls[mloc*264 + ck*8];
            int m = (int)bm*256 + half*128 + mloc;
            int col = (int)bn*256 + ck*8;
            int part = col / 768;
            int cb = col - part*768;
            int nh = cb / HD;
            int c = cb - nh*HD;
            int bflag = m >= L0;
            int l = m - (bflag ? L0 : 0);
            size_t addr = ((size_t)(part*16 + bflag*8 + nh)*L0 + l)*HD + c;
            *(bf16x8*)&Out[addr] = v;
        }
    }
}

// ---------------- 128x128 MFMA GEMM (R6 structure) — used for proj & fallback ----
template<int MODE>
__global__ __launch_bounds__(256) void gemm_bt(
    const bf16* __restrict__ A, const bf16* __restrict__ B,
    const float* __restrict__ bias, void* __restrict__ Out,
    int M, int N, int K, int NBN, int gelu_cols)
{
    __shared__ bf16 sh[2*16384];     // [buf][A:8192|B:8192] elements = 64 KiB
    const int tid = threadIdx.x;
    const int lane = tid & 63;
    const int w = tid >> 6;
    const int wr = w >> 1, wc = w & 1;

    const int nwg = gridDim.x;
    const int q_ = nwg >> 3, r_ = nwg & 7;
    const int xcd = blockIdx.x & 7, off = blockIdx.x >> 3;
    const int swz = (xcd < r_ ? xcd*(q_+1) : r_*(q_+1) + (xcd - r_)*q_) + off;
    const long bn = swz % NBN, bm = swz / NBN;

    f32x4 acc[4][4];
#pragma unroll
    for (int i = 0; i < 4; ++i)
#pragma unroll
        for (int j = 0; j < 4; ++j) acc[i][j] = (f32x4){0.f,0.f,0.f,0.f};

    const int trow = tid >> 3;                       // 0..31
    const int tchunk = (tid & 7) ^ (trow & 7);       // inverse swizzle (involution)
    const bf16* Ag = A + (bm*128 + trow)*(long)K + tchunk*8;
    const bf16* Bg = B + (bn*128 + trow)*(long)K + tchunk*8;

    const int arow = lane & 15;
    const int g8 = (lane >> 4) * 8;
    const int aswz = (arow & 7) * 8;                 // element-XOR for ds_read

    auto stage = [&](int buf, int kt) {
        const bf16* Asrc = Ag + (long)kt*64;
        const bf16* Bsrc = Bg + (long)kt*64;
        bf16* ldsA = sh + buf*16384;
        bf16* ldsB = sh + buf*16384 + 8192;
#pragma unroll
        for (int s = 0; s < 4; ++s) {
            __builtin_amdgcn_global_load_lds(GPTR(Asrc + (long)s*32*K), LPTR(ldsA + s*2048 + tid*8), 16, 0, 0);
            __builtin_amdgcn_global_load_lds(GPTR(Bsrc + (long)s*32*K), LPTR(ldsB + s*2048 + tid*8), 16, 0, 0);
        }
    };
    auto compute = [&](int buf) {
        const bf16* ldsA = sh + buf*16384;
        const bf16* ldsB = sh + buf*16384 + 8192;
#pragma unroll
        for (int kk = 0; kk < 2; ++kk) {
            bf16x8 af[4], bfr[4];
#pragma unroll
            for (int i = 0; i < 4; ++i)
                af[i] = *(const bf16x8*)&ldsA[(wr*64 + i*16 + arow)*64 + ((kk*32 + g8) ^ aswz)];
#pragma unroll
            for (int j = 0; j < 4; ++j)
                bfr[j] = *(const bf16x8*)&ldsB[(wc*64 + j*16 + arow)*64 + ((kk*32 + g8) ^ aswz)];
#pragma unroll
            for (int i = 0; i < 4; ++i)
#pragma unroll
                for (int j = 0; j < 4; ++j)
                    acc[i][j] = __builtin_amdgcn_mfma_f32_16x16x32_bf16(af[i], bfr[j], acc[i][j], 0, 0, 0);
        }
    };

    const int nkt = K / 64;
    stage(0, 0);
    for (int kt = 0; kt < nkt; ++kt) {
        if (kt + 1 < nkt) {
            stage((kt + 1) & 1, kt + 1);
            asm volatile("s_waitcnt vmcnt(8)" ::: "memory");
        } else {
            asm volatile("s_waitcnt vmcnt(0)" ::: "memory");
        }
        __builtin_amdgcn_s_barrier();
        __builtin_amdgcn_sched_barrier(0);
        compute(kt & 1);
        __builtin_amdgcn_sched_barrier(0);
        __builtin_amdgcn_s_barrier();
    }

    if (MODE == 1) {
#pragma unroll
        for (int j = 0; j < 4; ++j) {
            const int col = (int)bn*128 + wc*64 + j*16 + (lane & 15);
            const float bcol = bias[col];
#pragma unroll
            for (int i = 0; i < 4; ++i) {
                int row0 = (int)bm*128 + wr*64 + i*16 + ((lane>>4)<<2);
#pragma unroll
                for (int r = 0; r < 4; ++r)
                    ((float*)Out)[(size_t)(row0 + r)*N + col] = acc[i][j][r] + bcol;
            }
        }
    } else {
        bf16* tls = sh;
#pragma unroll
        for (int j = 0; j < 4; ++j) {
            const int colb = (int)bn*128 + wc*64 + j*16;
            const int lcol = wc*64 + j*16 + (lane & 15);
            const float bcol = bias[colb + (lane & 15)];
            const bool do_gelu = colb < gelu_cols;
#pragma unroll
            for (int i = 0; i < 4; ++i) {
                int lrow0 = wr*64 + i*16 + ((lane>>4)<<2);
#pragma unroll
                for (int r = 0; r < 4; ++r) {
                    float vacc = acc[i][j][r] + bcol;
                    if (do_gelu) vacc = fast_gelu(vacc);
                    tls[(lrow0 + r)*136 + lcol] = (bf16)vacc;
                }
            }
        }
        __syncthreads();
#pragma unroll
        for (int it = 0; it < 8; ++it) {
            int idx = it*256 + tid;
            int mloc = idx >> 4;
            int ck = idx & 15;
            bf16x8 v = *(const bf16x8*)&tls[mloc*136 + ck*8];
            int m = (int)bm*128 + mloc;
            int col = (int)bn*128 + ck*8;
            int part = col / 768;
            int cb = col - part*768;
            int nh = cb / HD;
            int c = cb - nh*HD;
            int bflag = m >= L0;
            int l = m - (bflag ? L0 : 0);
            size_t addr = ((size_t)(part*16 + bflag*8 + nh)*L0 + l)*HD + c;
            *(bf16x8*)&((bf16*)Out)[addr] = v;
        }
    }
}

// ---------------- depthwise conv3d (k=3, pad=1, stride (1,ST,ST)), bf16 out ----------
template<int ST, int HP, int WP, int MODE, int LP, bool GELU_IN>
__global__ __launch_bounds__(256) void dwconv2(
    const bf16* __restrict__ in, const float* __restrict__ w,
    bf16* __restrict__ out, int total)
{
    __shared__ float lw[27*HD];
    for (int i = threadIdx.x; i < 27*HD; i += 256) {
        int c = i / 27, tap = i % 27;
        lw[tap*HD + c] = w[i];
    }
    __syncthreads();
    int idx = blockIdx.x*256 + threadIdx.x;
    if (idx >= total) return;         // total = 16*HP*WP*12
    int c8 = idx % 12;
    int p = idx / 12;
    int xo = p % WP;
    int yo = (p / WP) % HP;
    int bh = p / (WP*HP);
    const bf16* ip = in + (size_t)bh * L0 * HD + c8*8;

    float acc[T0][8];
#pragma unroll
    for (int t = 0; t < T0; ++t)
#pragma unroll
        for (int j = 0; j < 8; ++j) acc[t][j] = 0.f;

#pragma unroll
    for (int dy = 0; dy < 3; ++dy) {
        int y = yo*ST + dy - 1;
        if ((unsigned)y >= (unsigned)H0) continue;
#pragma unroll
        for (int dx = 0; dx < 3; ++dx) {
            int x = xo*ST + dx - 1;
            if ((unsigned)x >= (unsigned)W0) continue;
            float wreg[3][8];
#pragma unroll
            for (int dt = 0; dt < 3; ++dt)
#pragma unroll
                for (int j = 0; j < 8; ++j)
                    wreg[dt][j] = lw[(dt*9 + dy*3 + dx)*HD + c8*8 + j];
            const bf16* colp = ip + ((size_t)(y*W0 + x))*HD;
#pragma unroll
            for (int t = 0; t < T0; ++t) {
                bf16x8 v = *(const bf16x8*)(colp + (size_t)t*H0*W0*HD);
                float f[8];
#pragma unroll
                for (int j = 0; j < 8; ++j) {
                    f[j] = (float)v[j];
                    if (GELU_IN) f[j] = fast_gelu(f[j]);
                }
#pragma unroll
                for (int dt = 0; dt < 3; ++dt) {
                    int to = t - dt + 1;
                    if (to < 0 || to >= T0) continue;
#pragma unroll
                    for (int j = 0; j < 8; ++j)
                        acc[to][j] += wreg[dt][j] * f[j];
                }
            }
        }
    }

#pragma unroll
    for (int to = 0; to < T0; ++to) {
        int l = (to*HP + yo)*WP + xo;
        if (MODE == 2) {
#pragma unroll
            for (int j = 0; j < 8; ++j)
                out[((size_t)bh*HD + c8*8 + j)*LP + l] = (bf16)acc[to][j];
        } else {
            bf16x8 ov;
#pragma unroll
            for (int j = 0; j < 8; ++j) ov[j] = (bf16)acc[to][j];
            *(bf16x8*)&out[((size_t)bh*LP + l)*HD + c8*8] = ov;
        }
    }
}

// ---------------- MFMA attention: block = (b,h) x 64 q rows, wave = 16 q rows -------
__global__ __launch_bounds__(256) void attn_mfma(
    const bf16* __restrict__ q, const bf16* __restrict__ k,
    const bf16* __restrict__ vt, bf16* __restrict__ out)
{
    const int tid = threadIdx.x;
    const int lane = tid & 63;
    const int w = tid >> 6;
    const int col = lane & 15;
    const int g = lane >> 4;
    const int blk = blockIdx.x;
    const int qblk = blk % (LQ/64);
    const int bh = blk / (LQ/64);
    const int q0 = qblk*64 + w*16;

    const bf16* Qp  = q  + ((size_t)bh*LQ + q0)*HD;
    const bf16* Kp  = k  + (size_t)bh*LKP*HD;
    const bf16* VTp = vt + (size_t)bh*HD*LKP;

    bf16x8 qf[3];
#pragma unroll
    for (int c = 0; c < 3; ++c)
        qf[c] = *(const bf16x8*)&Qp[(size_t)col*HD + c*32 + g*8];

    f32x4 o[6];
#pragma unroll
    for (int t = 0; t < 6; ++t) o[t] = (f32x4){0.f,0.f,0.f,0.f};
    float lsum = 0.f;

    for (int kc = 0; kc < LKP/32; ++kc) {
        const int kvb = kc*32;
        uint32_t P[2][2];
#pragma unroll
        for (int s = 0; s < 2; ++s) {
            f32x4 acc = (f32x4){0.f,0.f,0.f,0.f};
#pragma unroll
            for (int c = 0; c < 3; ++c) {
                bf16x8 kf = *(const bf16x8*)&Kp[(size_t)(kvb + s*16 + col)*HD + c*32 + g*8];
                acc = __builtin_amdgcn_mfma_f32_16x16x32_bf16(kf, qf[c], acc, 0, 0, 0);
            }
            bf16x4 pb;
#pragma unroll
            for (int r = 0; r < 4; ++r) {
                int kv = kvb + s*16 + g*4 + r;
                float p = (kv < LK) ? __expf(acc[r]*SCALE) : 0.f;
                lsum += p;
                pb[r] = (bf16)p;
            }
            union { bf16x4 v; uint32_t u[2]; } pk; pk.v = pb;
            P[s][0] = pk.u[0]; P[s][1] = pk.u[1];
        }
        uint32_t sa0 = (g < 2) ? P[1][0] : P[0][0];
        uint32_t sa1 = (g < 2) ? P[1][1] : P[0][1];
        uint32_t tb0 = (g < 2) ? P[0][0] : P[1][0];
        uint32_t tb1 = (g < 2) ? P[0][1] : P[1][1];
        uint32_t R32_0 = (uint32_t)__shfl_xor((int)sa0, 32);
        uint32_t R32_1 = (uint32_t)__shfl_xor((int)sa1, 32);
        uint32_t R48_0 = (uint32_t)__shfl_xor((int)sa0, 48);
        uint32_t R48_1 = (uint32_t)__shfl_xor((int)sa1, 48);
        uint32_t R16_0 = (uint32_t)__shfl_xor((int)tb0, 16);
        uint32_t R16_1 = (uint32_t)__shfl_xor((int)tb1, 16);
        union { uint32_t u[4]; bf16x8 v; } pf;
        pf.u[0] = (g == 0) ? P[0][0] : (g == 1) ? R48_0 : (g == 2) ? R32_0 : R16_0;
        pf.u[1] = (g == 0) ? P[0][1] : (g == 1) ? R48_1 : (g == 2) ? R32_1 : R16_1;
        pf.u[2] = (g == 0) ? R16_0 : (g == 1) ? R32_0 : (g == 2) ? R48_0 : P[1][0];
        pf.u[3] = (g == 0) ? R16_1 : (g == 1) ? R32_1 : (g == 2) ? R48_1 : P[1][1];
#pragma unroll
        for (int t = 0; t < 6; ++t) {
            bf16x8 vf = *(const bf16x8*)&VTp[(size_t)(t*16 + col)*LKP + kvb + g*8];
            o[t] = __builtin_amdgcn_mfma_f32_16x16x32_bf16(vf, pf.v, o[t], 0, 0, 0);
        }
    }

    lsum += __shfl_xor(lsum, 16);
    lsum += __shfl_xor(lsum, 32);
    float inv = 1.f / lsum;

    const int b = bh >> 3, nh = bh & 7;
    size_t obase = ((size_t)b*LQ + q0 + col)*CDIM + (size_t)nh*HD;
#pragma unroll
    for (int t = 0; t < 6; ++t) {
        bf16x4 qres = *(const bf16x4*)&Qp[(size_t)col*HD + t*16 + g*4];
        bf16x4 ov;
#pragma unroll
        for (int r = 0; r < 4; ++r)
            ov[r] = (bf16)(o[t][r]*inv + (float)qres[r]);
        *(bf16x4*)&out[obase + t*16 + g*4] = ov;
    }
}

extern "C" void kernel_launch(void* const* d_in, const int* in_sizes, int n_in,
                              void* d_out, int out_size, void* d_ws, size_t ws_size,
                              hipStream_t stream) {
    const float* x      = (const float*)d_in[0];
    const float* qkv_w  = (const float*)d_in[1];
    const float* qkv_b  = (const float*)d_in[2];
    const float* proj_w = (const float*)d_in[3];
    const float* proj_b = (const float*)d_in[4];
    const float* pq_w   = (const float*)d_in[5];
    const float* pk_w   = (const float*)d_in[6];
    const float* pv_w   = (const float*)d_in[7];

    uint8_t* ws = (uint8_t*)d_ws;
    const bool fused = ws_size >= 355000000ull;

    bf16 *x_bf, *qkv_g, *wqkv_bf, *wproj_bf, *q_bf, *k_bf, *vt_bf, *attn_o;
    x_bf = (bf16*)ws;                              // 77,070,336 B
    if (fused) {
        qkv_g    = (bf16*)(ws +  77070336);        // 231,211,008 B: [3][16][L0][96]
        wqkv_bf  = (bf16*)(ws + 308281344);        // 3,538,944 B
        wproj_bf = (bf16*)(ws + 311820288);        // 1,179,648 B
        q_bf     = (bf16*)(ws + 312999936);        // 19,267,584 B [16][6272][96]
        k_bf     = (bf16*)(ws + 332267520);        // 1,277,952 B  [16][416][96]
        vt_bf    = (bf16*)(ws + 333545472);        // 1,277,952 B  [16][96][416]
        attn_o   = (bf16*)(ws + 334823424);        // 19,267,584 B -> end 354,091,008
    } else {
        qkv_g    = (bf16*)(ws +  77070336);
        wqkv_bf  = (bf16*)(ws + 154140672);
        wproj_bf = (bf16*)(ws + 157679616);
        q_bf     = (bf16*)(ws + 158859264);
        k_bf     = (bf16*)(ws + 178126848);
        vt_bf    = (bf16*)(ws + 179404800);
        attn_o   = (bf16*)(ws + 180682752);
    }

    hipMemsetAsync(k_bf, 0, 1277952, stream);
    hipMemsetAsync(vt_bf, 0, 1277952, stream);

    cvt4<<<2048, 256, 0, stream>>>((const f4*)x, (bf16x4*)x_bf, 38535168/4);
    cvt4<<<1728, 256, 0, stream>>>((const f4*)qkv_w, (bf16x4*)wqkv_bf, 1769472/4);
    cvt4<<<576, 256, 0, stream>>>((const f4*)proj_w, (bf16x4*)wproj_bf, 589824/4);

    const size_t PART = (size_t)16*L0*HD;
    if (fused) {
        // qkv GEMM: M=50176 (196 bm), N=2304 (9 bn), K=768. 256^2 8-wave 4-phase.
        gemm256_qkv<<<196*9, 512, 0, stream>>>(
            x_bf, wqkv_bf, qkv_b, qkv_g, 768, 9);
        dwconv2<2, HP_Q, WP_Q, 0, LQ, false><<<588, 256, 0, stream>>>(
            qkv_g, pq_w, q_bf, 16*HP_Q*WP_Q*12);
        dwconv2<8, HP_K, WP_K, 1, LKP, true><<<37, 256, 0, stream>>>(
            qkv_g + PART, pk_w, k_bf, 16*HP_K*WP_K*12);
        dwconv2<8, HP_K, WP_K, 2, LKP, true><<<37, 256, 0, stream>>>(
            qkv_g + 2*PART, pv_w, vt_bf, 16*HP_K*WP_K*12);
    } else {
        for (int p = 0; p < 3; ++p) {
            gemm_bt<0><<<6*392, 256, 0, stream>>>(
                x_bf, wqkv_bf + (size_t)p*768*768, qkv_b + p*768, qkv_g,
                50176, 768, 768, 6, p == 0 ? 768 : 0);
            if (p == 0)
                dwconv2<2, HP_Q, WP_Q, 0, LQ, false><<<588, 256, 0, stream>>>(
                    qkv_g, pq_w, q_bf, 16*HP_Q*WP_Q*12);
            else if (p == 1)
                dwconv2<8, HP_K, WP_K, 1, LKP, true><<<37, 256, 0, stream>>>(
                    qkv_g, pk_w, k_bf, 16*HP_K*WP_K*12);
            else
                dwconv2<8, HP_K, WP_K, 2, LKP, true><<<37, 256, 0, stream>>>(
                    qkv_g, pv_w, vt_bf, 16*HP_K*WP_K*12);
        }
    }

    attn_mfma<<<16*(LQ/64), 256, 0, stream>>>(q_bf, k_bf, vt_bf, attn_o);

    gemm_bt<1><<<6*98, 256, 0, stream>>>(
        attn_o, wproj_bf, proj_b, d_out, 12544, 768, 768, 6, 0);
}

// Round 8
// 340.911 us; speedup vs baseline: 1.4857x; 1.4857x over previous
//
#include <hip/hip_runtime.h>
#include <cstdint>

#define NH 8
#define HD 96
#define CDIM 768
#define BQ 2
#define T0 8
#define H0 56
#define W0 56
#define L0 (T0*H0*W0)     // 25088
#define HP_Q 28
#define WP_Q 28
#define LQ (T0*HP_Q*WP_Q) // 6272
#define HP_K 7
#define WP_K 7
#define LK (T0*HP_K*WP_K) // 392
#define LKP 416           // kv padded to multiple of 32
#define SCALE 0.10206207261596577f
// compact KV token grid: 20 y-values x 20 x-values actually touched by stride-8 conv
#define NYC 20
#define MKV 6400          // 2*8*400 rows; padded to 6528 = 51*128 in grid math (50 full blocks)

typedef __bf16 bf16;
typedef bf16 bf16x4 __attribute__((ext_vector_type(4)));
typedef bf16 bf16x8 __attribute__((ext_vector_type(8)));
typedef float f32x4 __attribute__((ext_vector_type(4)));
typedef float f4 __attribute__((ext_vector_type(4)));

#define GPTR(x) ((const __attribute__((address_space(1))) void*)(x))
#define LPTR(x) ((__attribute__((address_space(3))) void*)(x))

// fast erf-GELU: A&S 7.1.27 rational erf approx, |err(erf)| <= 5e-4 (<< bf16 rounding)
__device__ __forceinline__ float fast_gelu(float x) {
    float z = __builtin_fabsf(x) * 0.7071067811865476f;
    float p = 1.f + z*(0.278393f + z*(0.230389f + z*(0.000972f + z*0.078108f)));
    p = p * p;
    p = p * p;
    float e = 1.f - __builtin_amdgcn_rcpf(p);   // erf(|x|/sqrt2)
    float erfv = (x < 0.f) ? -e : e;
    return 0.5f * x * (1.f + erfv);
}

// ---------------- fp32 -> bf16 conversion ----------------
__global__ void cvt4(const f4* __restrict__ in, bf16x4* __restrict__ out, long n4) {
    long i = (long)blockIdx.x * blockDim.x + threadIdx.x;
    long stride = (long)gridDim.x * blockDim.x;
    for (; i < n4; i += stride) {
        f4 v = in[i];
        bf16x4 o;
        o.x = (bf16)v.x; o.y = (bf16)v.y; o.z = (bf16)v.z; o.w = (bf16)v.w;
        out[i] = o;
    }
}

// map compact grid index (0..19) -> original spatial coord (y or x)
__device__ __forceinline__ int cmap(int i) {
    return ((i + 1) / 3) * 8 + (i + 1) % 3 - 1;
}

// ---------------- 128x128 MFMA GEMM: out[m,n] = sum_k A[m,k]*B[n,k] + bias[n] -------
// T1 XCD swizzle + T2 LDS XOR swizzle + dbuf + counted vmcnt (R6 structure).
// MODE 0: q-part.  A rows linear, N=768. GELU all cols; scatter bf16 [16][L0][96].
// MODE 1: proj.    fp32 out[m*N+n].
// MODE 2: kv-compact. A rows GATHERED from the 400 touched tokens; N=1536;
//         GELU; store bf16 compact [part][b*8+nh][t*400+rr][96].
template<int MODE>
__global__ __launch_bounds__(256) void gemm_bt(
    const bf16* __restrict__ A, const bf16* __restrict__ B,
    const float* __restrict__ bias, void* __restrict__ Out,
    int M, int N, int K, int NBN, int gelu_cols)
{
    __shared__ bf16 sh[2*16384];     // [buf][A:8192|B:8192] elements = 64 KiB
    const int tid = threadIdx.x;
    const int lane = tid & 63;
    const int w = tid >> 6;
    const int wr = w >> 1, wc = w & 1;

    const int nwg = gridDim.x;
    const int q_ = nwg >> 3, r_ = nwg & 7;
    const int xcd = blockIdx.x & 7, off = blockIdx.x >> 3;
    const int swz = (xcd < r_ ? xcd*(q_+1) : r_*(q_+1) + (xcd - r_)*q_) + off;
    const long bn = swz % NBN, bm = swz / NBN;

    f32x4 acc[4][4];
#pragma unroll
    for (int i = 0; i < 4; ++i)
#pragma unroll
        for (int j = 0; j < 4; ++j) acc[i][j] = (f32x4){0.f,0.f,0.f,0.f};

    const int trow = tid >> 3;                       // 0..31
    const int tchunk = (tid & 7) ^ (trow & 7);       // inverse swizzle (involution)

    // A source row offsets for the 4 staged slabs (gathered in MODE 2)
    long aoff[4];
#pragma unroll
    for (int s = 0; s < 4; ++s) {
        int rA = (int)bm*128 + s*32 + trow;
        if (MODE == 2) {
            int mm = rA < MKV ? rA : 0;
            int b = mm / 3200; int r = mm - b*3200;
            int t = r / 400;  int rr = r - t*400;
            int yi = rr / NYC, xi = rr - yi*NYC;
            int y = cmap(yi), x = cmap(xi);
            aoff[s] = ((long)b*L0 + (t*H0 + y)*W0 + x) * (long)K;
        } else {
            aoff[s] = (long)rA * K;
        }
    }
    const bf16* Bg = B + (bn*128 + trow)*(long)K + tchunk*8;

    const int arow = lane & 15;
    const int g8 = (lane >> 4) * 8;
    const int aswz = (arow & 7) * 8;                 // element-XOR for ds_read

    auto stage = [&](int buf, int kt) {
        bf16* ldsA = sh + buf*16384;
        bf16* ldsB = sh + buf*16384 + 8192;
#pragma unroll
        for (int s = 0; s < 4; ++s) {
            __builtin_amdgcn_global_load_lds(GPTR(A + aoff[s] + kt*64 + tchunk*8),
                                             LPTR(ldsA + s*2048 + tid*8), 16, 0, 0);
            __builtin_amdgcn_global_load_lds(GPTR(Bg + (long)kt*64 + (long)s*32*K),
                                             LPTR(ldsB + s*2048 + tid*8), 16, 0, 0);
        }
    };
    auto compute = [&](int buf) {
        const bf16* ldsA = sh + buf*16384;
        const bf16* ldsB = sh + buf*16384 + 8192;
#pragma unroll
        for (int kk = 0; kk < 2; ++kk) {
            bf16x8 af[4], bfr[4];
#pragma unroll
            for (int i = 0; i < 4; ++i)
                af[i] = *(const bf16x8*)&ldsA[(wr*64 + i*16 + arow)*64 + ((kk*32 + g8) ^ aswz)];
#pragma unroll
            for (int j = 0; j < 4; ++j)
                bfr[j] = *(const bf16x8*)&ldsB[(wc*64 + j*16 + arow)*64 + ((kk*32 + g8) ^ aswz)];
            __builtin_amdgcn_s_setprio(1);
#pragma unroll
            for (int i = 0; i < 4; ++i)
#pragma unroll
                for (int j = 0; j < 4; ++j)
                    acc[i][j] = __builtin_amdgcn_mfma_f32_16x16x32_bf16(af[i], bfr[j], acc[i][j], 0, 0, 0);
            __builtin_amdgcn_s_setprio(0);
        }
    };

    const int nkt = K / 64;
    stage(0, 0);
    for (int kt = 0; kt < nkt; ++kt) {
        if (kt + 1 < nkt) {
            stage((kt + 1) & 1, kt + 1);
            asm volatile("s_waitcnt vmcnt(8)" ::: "memory");   // kt's 8 loads landed
        } else {
            asm volatile("s_waitcnt vmcnt(0)" ::: "memory");
        }
        __builtin_amdgcn_s_barrier();
        __builtin_amdgcn_sched_barrier(0);
        compute(kt & 1);
        __builtin_amdgcn_sched_barrier(0);
        __builtin_amdgcn_s_barrier();
    }

    // ---------------- epilogue ----------------
    if (MODE == 1) {
#pragma unroll
        for (int j = 0; j < 4; ++j) {
            const int col = (int)bn*128 + wc*64 + j*16 + (lane & 15);
            const float bcol = bias[col];
#pragma unroll
            for (int i = 0; i < 4; ++i) {
                int row0 = (int)bm*128 + wr*64 + i*16 + ((lane>>4)<<2);
#pragma unroll
                for (int r = 0; r < 4; ++r)
                    ((float*)Out)[(size_t)(row0 + r)*N + col] = acc[i][j][r] + bcol;
            }
        }
    } else {
        // stage tile into LDS (bf16, padded 136 cols), then coalesced bf16x8 stores
        bf16* tls = sh;
#pragma unroll
        for (int j = 0; j < 4; ++j) {
            const int colb = (int)bn*128 + wc*64 + j*16;
            const int lcol = wc*64 + j*16 + (lane & 15);
            const float bcol = bias[colb + (lane & 15)];
            const bool do_gelu = (MODE == 2) || (colb < gelu_cols);
#pragma unroll
            for (int i = 0; i < 4; ++i) {
                int lrow0 = wr*64 + i*16 + ((lane>>4)<<2);
#pragma unroll
                for (int r = 0; r < 4; ++r) {
                    float vacc = acc[i][j][r] + bcol;
                    if (do_gelu) vacc = fast_gelu(vacc);
                    tls[(lrow0 + r)*136 + lcol] = (bf16)vacc;
                }
            }
        }
        __syncthreads();
#pragma unroll
        for (int it = 0; it < 8; ++it) {
            int idx = it*256 + tid;
            int mloc = idx >> 4;
            int ck = idx & 15;
            bf16x8 v = *(const bf16x8*)&tls[mloc*136 + ck*8];
            int m = (int)bm*128 + mloc;
            int col = (int)bn*128 + ck*8;
            if (MODE == 0) {
                int nh = col / HD;
                int c = col - nh*HD;
                int bflag = m >= L0;                  // M = 2*L0
                int l = m - (bflag ? L0 : 0);
                size_t addr = ((size_t)(bflag*8 + nh)*L0 + l)*HD + c;
                *(bf16x8*)&((bf16*)Out)[addr] = v;
            } else { // MODE 2: compact [part][b*8+nh][t*400+rr][96]
                if (m < MKV) {
                    int part = col / 768;
                    int cb = col - part*768;
                    int nh = cb / HD;
                    int c = cb - nh*HD;
                    int b = m / 3200; int r = m - b*3200;   // r = t*400 + rr
                    size_t addr = ((size_t)(part*16 + b*8 + nh)*3200 + r)*HD + c;
                    *(bf16x8*)&((bf16*)Out)[addr] = v;
                }
            }
        }
    }
}

// ---------------- depthwise conv3d q-path (k=3, pad=1, stride (1,2,2)), bf16 out ----
// thread = (bh, yo, xo, c8): computes all T0 'to' outputs for 8 channels.
__global__ __launch_bounds__(256) void dwconv_q(
    const bf16* __restrict__ in, const float* __restrict__ w,
    bf16* __restrict__ out, int total)
{
    __shared__ float lw[27*HD];
    for (int i = threadIdx.x; i < 27*HD; i += 256) {
        int c = i / 27, tap = i % 27;
        lw[tap*HD + c] = w[i];
    }
    __syncthreads();
    int idx = blockIdx.x*256 + threadIdx.x;
    if (idx >= total) return;         // total = 16*HP_Q*WP_Q*12
    int c8 = idx % 12;
    int p = idx / 12;
    int xo = p % WP_Q;
    int yo = (p / WP_Q) % HP_Q;
    int bh = p / (WP_Q*HP_Q);
    const bf16* ip = in + (size_t)bh * L0 * HD + c8*8;

    float acc[T0][8];
#pragma unroll
    for (int t = 0; t < T0; ++t)
#pragma unroll
        for (int j = 0; j < 8; ++j) acc[t][j] = 0.f;

#pragma unroll
    for (int dy = 0; dy < 3; ++dy) {
        int y = yo*2 + dy - 1;
        if ((unsigned)y >= (unsigned)H0) continue;
#pragma unroll
        for (int dx = 0; dx < 3; ++dx) {
            int x = xo*2 + dx - 1;
            if ((unsigned)x >= (unsigned)W0) continue;
            float wreg[3][8];
#pragma unroll
            for (int dt = 0; dt < 3; ++dt)
#pragma unroll
                for (int j = 0; j < 8; ++j)
                    wreg[dt][j] = lw[(dt*9 + dy*3 + dx)*HD + c8*8 + j];
            const bf16* colp = ip + ((size_t)(y*W0 + x))*HD;
#pragma unroll
            for (int t = 0; t < T0; ++t) {
                bf16x8 v = *(const bf16x8*)(colp + (size_t)t*H0*W0*HD);
                float f[8];
#pragma unroll
                for (int j = 0; j < 8; ++j) f[j] = (float)v[j];
#pragma unroll
                for (int dt = 0; dt < 3; ++dt) {
                    int to = t - dt + 1;
                    if (to < 0 || to >= T0) continue;
#pragma unroll
                    for (int j = 0; j < 8; ++j)
                        acc[to][j] += wreg[dt][j] * f[j];
                }
            }
        }
    }

#pragma unroll
    for (int to = 0; to < T0; ++to) {
        int l = (to*HP_Q + yo)*WP_Q + xo;
        bf16x8 ov;
#pragma unroll
        for (int j = 0; j < 8; ++j) ov[j] = (bf16)acc[to][j];
        *(bf16x8*)&out[((size_t)bh*LQ + l)*HD + c8*8] = ov;
    }
}

// ---------------- depthwise conv3d K/V from COMPACT input [16][8][400][96] ----------
// MODE 1: k -> out[bh][l][c] (LP=LKP rows, pad pre-zeroed)
// MODE 2: v -> out[bh][c][l] (transposed; pad cols pre-zeroed)
template<int MODE>
__global__ __launch_bounds__(256) void dwconv_kv(
    const bf16* __restrict__ in, const float* __restrict__ w,
    bf16* __restrict__ out, int total)
{
    __shared__ float lw[27*HD];
    for (int i = threadIdx.x; i < 27*HD; i += 256) {
        int c = i / 27, tap = i % 27;
        lw[tap*HD + c] = w[i];
    }
    __syncthreads();
    int idx = blockIdx.x*256 + threadIdx.x;
    if (idx >= total) return;         // total = 16*7*7*12
    int c8 = idx % 12;
    int p = idx / 12;
    int xo = p % WP_K;
    int yo = (p / WP_K) % HP_K;
    int bh = p / (WP_K*HP_K);
    const bf16* ip = in + (size_t)bh * 3200 * HD + c8*8;

    float acc[T0][8];
#pragma unroll
    for (int t = 0; t < T0; ++t)
#pragma unroll
        for (int j = 0; j < 8; ++j) acc[t][j] = 0.f;

#pragma unroll
    for (int dy = 0; dy < 3; ++dy) {
        int yi = 3*yo + dy - 1;
        if ((unsigned)yi >= (unsigned)NYC) continue;
#pragma unroll
        for (int dx = 0; dx < 3; ++dx) {
            int xi = 3*xo + dx - 1;
            if ((unsigned)xi >= (unsigned)NYC) continue;
            float wreg[3][8];
#pragma unroll
            for (int dt = 0; dt < 3; ++dt)
#pragma unroll
                for (int j = 0; j < 8; ++j)
                    wreg[dt][j] = lw[(dt*9 + dy*3 + dx)*HD + c8*8 + j];
            const bf16* colp = ip + ((size_t)(yi*NYC + xi))*HD;
#pragma unroll
            for (int t = 0; t < T0; ++t) {
                bf16x8 v = *(const bf16x8*)(colp + (size_t)t*400*HD);
                float f[8];
#pragma unroll
                for (int j = 0; j < 8; ++j) f[j] = (float)v[j];
#pragma unroll
                for (int dt = 0; dt < 3; ++dt) {
                    int to = t - dt + 1;
                    if (to < 0 || to >= T0) continue;
#pragma unroll
                    for (int j = 0; j < 8; ++j)
                        acc[to][j] += wreg[dt][j] * f[j];
                }
            }
        }
    }

#pragma unroll
    for (int to = 0; to < T0; ++to) {
        int l = (to*HP_K + yo)*WP_K + xo;
        if (MODE == 2) {
#pragma unroll
            for (int j = 0; j < 8; ++j)
                out[((size_t)bh*HD + c8*8 + j)*LKP + l] = (bf16)acc[to][j];
        } else {
            bf16x8 ov;
#pragma unroll
            for (int j = 0; j < 8; ++j) ov[j] = (bf16)acc[to][j];
            *(bf16x8*)&out[((size_t)bh*LKP + l)*HD + c8*8] = ov;
        }
    }
}

// ---------------- MFMA attention: block = (b,h) x 64 q rows, wave = 16 q rows -------
__global__ __launch_bounds__(256) void attn_mfma(
    const bf16* __restrict__ q, const bf16* __restrict__ k,
    const bf16* __restrict__ vt, bf16* __restrict__ out)
{
    const int tid = threadIdx.x;
    const int lane = tid & 63;
    const int w = tid >> 6;
    const int col = lane & 15;
    const int g = lane >> 4;
    const int blk = blockIdx.x;
    const int qblk = blk % (LQ/64);
    const int bh = blk / (LQ/64);
    const int q0 = qblk*64 + w*16;

    const bf16* Qp  = q  + ((size_t)bh*LQ + q0)*HD;
    const bf16* Kp  = k  + (size_t)bh*LKP*HD;
    const bf16* VTp = vt + (size_t)bh*HD*LKP;

    bf16x8 qf[3];
#pragma unroll
    for (int c = 0; c < 3; ++c)
        qf[c] = *(const bf16x8*)&Qp[(size_t)col*HD + c*32 + g*8];

    f32x4 o[6];
#pragma unroll
    for (int t = 0; t < 6; ++t) o[t] = (f32x4){0.f,0.f,0.f,0.f};
    float lsum = 0.f;

    for (int kc = 0; kc < LKP/32; ++kc) {
        const int kvb = kc*32;
        uint32_t P[2][2];
#pragma unroll
        for (int s = 0; s < 2; ++s) {
            f32x4 acc = (f32x4){0.f,0.f,0.f,0.f};
#pragma unroll
            for (int c = 0; c < 3; ++c) {
                bf16x8 kf = *(const bf16x8*)&Kp[(size_t)(kvb + s*16 + col)*HD + c*32 + g*8];
                acc = __builtin_amdgcn_mfma_f32_16x16x32_bf16(kf, qf[c], acc, 0, 0, 0);
            }
            bf16x4 pb;
#pragma unroll
            for (int r = 0; r < 4; ++r) {
                int kv = kvb + s*16 + g*4 + r;
                float p = (kv < LK) ? __expf(acc[r]*SCALE) : 0.f;
                lsum += p;
                pb[r] = (bf16)p;
            }
            union { bf16x4 v; uint32_t u[2]; } pk; pk.v = pb;
            P[s][0] = pk.u[0]; P[s][1] = pk.u[1];
        }
        uint32_t sa0 = (g < 2) ? P[1][0] : P[0][0];
        uint32_t sa1 = (g < 2) ? P[1][1] : P[0][1];
        uint32_t tb0 = (g < 2) ? P[0][0] : P[1][0];
        uint32_t tb1 = (g < 2) ? P[0][1] : P[1][1];
        uint32_t R32_0 = (uint32_t)__shfl_xor((int)sa0, 32);
        uint32_t R32_1 = (uint32_t)__shfl_xor((int)sa1, 32);
        uint32_t R48_0 = (uint32_t)__shfl_xor((int)sa0, 48);
        uint32_t R48_1 = (uint32_t)__shfl_xor((int)sa1, 48);
        uint32_t R16_0 = (uint32_t)__shfl_xor((int)tb0, 16);
        uint32_t R16_1 = (uint32_t)__shfl_xor((int)tb1, 16);
        union { uint32_t u[4]; bf16x8 v; } pf;
        pf.u[0] = (g == 0) ? P[0][0] : (g == 1) ? R48_0 : (g == 2) ? R32_0 : R16_0;
        pf.u[1] = (g == 0) ? P[0][1] : (g == 1) ? R48_1 : (g == 2) ? R32_1 : R16_1;
        pf.u[2] = (g == 0) ? R16_0 : (g == 1) ? R32_0 : (g == 2) ? R48_0 : P[1][0];
        pf.u[3] = (g == 0) ? R16_1 : (g == 1) ? R32_1 : (g == 2) ? R48_1 : P[1][1];
#pragma unroll
        for (int t = 0; t < 6; ++t) {
            bf16x8 vf = *(const bf16x8*)&VTp[(size_t)(t*16 + col)*LKP + kvb + g*8];
            o[t] = __builtin_amdgcn_mfma_f32_16x16x32_bf16(vf, pf.v, o[t], 0, 0, 0);
        }
    }

    lsum += __shfl_xor(lsum, 16);
    lsum += __shfl_xor(lsum, 32);
    float inv = 1.f / lsum;

    const int b = bh >> 3, nh = bh & 7;
    size_t obase = ((size_t)b*LQ + q0 + col)*CDIM + (size_t)nh*HD;
#pragma unroll
    for (int t = 0; t < 6; ++t) {
        bf16x4 qres = *(const bf16x4*)&Qp[(size_t)col*HD + t*16 + g*4];
        bf16x4 ov;
#pragma unroll
        for (int r = 0; r < 4; ++r)
            ov[r] = (bf16)(o[t][r]*inv + (float)qres[r]);
        *(bf16x4*)&out[obase + t*16 + g*4] = ov;
    }
}

extern "C" void kernel_launch(void* const* d_in, const int* in_sizes, int n_in,
                              void* d_out, int out_size, void* d_ws, size_t ws_size,
                              hipStream_t stream) {
    const float* x      = (const float*)d_in[0];
    const float* qkv_w  = (const float*)d_in[1];
    const float* qkv_b  = (const float*)d_in[2];
    const float* proj_w = (const float*)d_in[3];
    const float* proj_b = (const float*)d_in[4];
    const float* pq_w   = (const float*)d_in[5];
    const float* pk_w   = (const float*)d_in[6];
    const float* pv_w   = (const float*)d_in[7];

    uint8_t* ws = (uint8_t*)d_ws;
    bf16* x_bf     = (bf16*)(ws);                  // 77,070,336 B
    bf16* qg_out   = (bf16*)(ws +  77070336);      // 77,070,336 B  [16][L0][96] (GELU'd Q)
    bf16* kv_c     = (bf16*)(ws + 154140672);      // 19,660,800 B  [2][16][3200][96]
    bf16* wqkv_bf  = (bf16*)(ws + 173801472);      // 3,538,944 B
    bf16* wproj_bf = (bf16*)(ws + 177340416);      // 1,179,648 B
    bf16* q_bf     = (bf16*)(ws + 178520064);      // 19,267,584 B  [16][6272][96]
    bf16* k_bf     = (bf16*)(ws + 197787648);      // 1,277,952 B   [16][416][96]
    bf16* vt_bf    = (bf16*)(ws + 199065600);      // 1,277,952 B   [16][96][416]
    bf16* attn_o   = (bf16*)(ws + 200343552);      // 19,267,584 B -> end 219,611,136

    hipMemsetAsync(k_bf, 0, 1277952, stream);
    hipMemsetAsync(vt_bf, 0, 1277952, stream);

    cvt4<<<2048, 256, 0, stream>>>((const f4*)x, (bf16x4*)x_bf, 38535168/4);
    cvt4<<<1728, 256, 0, stream>>>((const f4*)qkv_w, (bf16x4*)wqkv_bf, 1769472/4);
    cvt4<<<576, 256, 0, stream>>>((const f4*)proj_w, (bf16x4*)wproj_bf, 589824/4);

    // Q-part GEMM: M=50176, N=768 (GELU), scatter to [16][L0][96]
    gemm_bt<0><<<392*6, 256, 0, stream>>>(
        x_bf, wqkv_bf, qkv_b, qg_out, 50176, 768, 768, 6, 768);

    // K/V compact GEMM: M=6400 gathered rows, N=1536, GELU, compact store
    gemm_bt<2><<<50*12, 256, 0, stream>>>(
        x_bf, wqkv_bf + (size_t)768*768, qkv_b + 768, kv_c, MKV, 1536, 768, 12, 0);

    dwconv_q<<<588, 256, 0, stream>>>(qg_out, pq_w, q_bf, 16*HP_Q*WP_Q*12);
    dwconv_kv<1><<<37, 256, 0, stream>>>(kv_c, pk_w, k_bf, 16*HP_K*WP_K*12);
    dwconv_kv<2><<<37, 256, 0, stream>>>(kv_c + (size_t)16*3200*HD, pv_w, vt_bf, 16*HP_K*WP_K*12);

    attn_mfma<<<16*(LQ/64), 256, 0, stream>>>(q_bf, k_bf, vt_bf, attn_o);

    gemm_bt<1><<<6*98, 256, 0, stream>>>(
        attn_o, wproj_bf, proj_b, d_out, 12544, 768, 768, 6, 0);
}

// Round 9
// 326.270 us; speedup vs baseline: 1.5524x; 1.0449x over previous
//
#include <hip/hip_runtime.h>
#include <cstdint>

#define NH 8
#define HD 96
#define CDIM 768
#define BQ 2
#define T0 8
#define H0 56
#define W0 56
#define L0 (T0*H0*W0)     // 25088
#define HP_Q 28
#define WP_Q 28
#define LQ (T0*HP_Q*WP_Q) // 6272
#define HP_K 7
#define WP_K 7
#define LK (T0*HP_K*WP_K) // 392
#define LKP 416           // kv padded to multiple of 32
#define SCALE 0.10206207261596577f
// compact KV token grid: 20 y-values x 20 x-values actually touched by stride-8 conv
#define NYC 20
#define MKV 6400          // 2*8*400 rows

typedef __bf16 bf16;
typedef bf16 bf16x4 __attribute__((ext_vector_type(4)));
typedef bf16 bf16x8 __attribute__((ext_vector_type(8)));
typedef float f32x4 __attribute__((ext_vector_type(4)));
typedef float f4 __attribute__((ext_vector_type(4)));

#define GPTR(x) ((const __attribute__((address_space(1))) void*)(x))
#define LPTR(x) ((__attribute__((address_space(3))) void*)(x))

// fast erf-GELU: A&S 7.1.27 rational erf approx, |err(erf)| <= 5e-4 (<< bf16 rounding)
__device__ __forceinline__ float fast_gelu(float x) {
    float z = __builtin_fabsf(x) * 0.7071067811865476f;
    float p = 1.f + z*(0.278393f + z*(0.230389f + z*(0.000972f + z*0.078108f)));
    p = p * p;
    p = p * p;
    float e = 1.f - __builtin_amdgcn_rcpf(p);   // erf(|x|/sqrt2)
    float erfv = (x < 0.f) ? -e : e;
    return 0.5f * x * (1.f + erfv);
}

// ---------------- fused fp32 -> bf16 conversion (x, qkv_w, proj_w in one launch) ----
#define NX4 9633792
#define NW4 442368
#define NP4 147456
__global__ void cvt_all(const f4* __restrict__ x, const f4* __restrict__ wq,
                        const f4* __restrict__ wp, bf16x4* __restrict__ xo,
                        bf16x4* __restrict__ wqo, bf16x4* __restrict__ wpo) {
    const long total = (long)NX4 + NW4 + NP4;
    long stride = (long)gridDim.x * blockDim.x;
    for (long i = (long)blockIdx.x * blockDim.x + threadIdx.x; i < total; i += stride) {
        f4 v; bf16x4* o;
        if (i < NX4)            { v = x[i];            o = xo + i; }
        else if (i < NX4 + NW4) { v = wq[i - NX4];     o = wqo + (i - NX4); }
        else                    { v = wp[i - NX4 - NW4]; o = wpo + (i - NX4 - NW4); }
        bf16x4 t;
        t.x = (bf16)v.x; t.y = (bf16)v.y; t.z = (bf16)v.z; t.w = (bf16)v.w;
        *o = t;
    }
}

// map compact grid index (0..19) -> original spatial coord (y or x)
__device__ __forceinline__ int cmap(int i) {
    return ((i + 1) / 3) * 8 + (i + 1) % 3 - 1;
}

// ============ 256x256 8-wave 4-phase Q GEMM, counted vmcnt (T1+T2+T3/T4+T5) =========
// A[50176x768] @ B^T[768x768] + bias -> GELU -> scatter bf16 [16][L0][96].
// Per K-tile: prefetch t+1 interleaved 2-gloads-per-phase; single vmcnt(2) (never 0
// mid-loop); per-phase lgkmcnt(0)+sched_barrier+setprio; barriers only at tile edges.
// Write-after-read safety: prefetch into buf nxt issued only after the end-of-tile
// barrier that retired all reads of nxt (tile t-1).
__global__ __launch_bounds__(512, 2) void gemm256_q(
    const bf16* __restrict__ A, const bf16* __restrict__ B,
    const float* __restrict__ bias, bf16* __restrict__ Out)
{
    __shared__ bf16 sh[2*32768];     // 2 bufs x (A 16384 | B 16384) elems = 128 KiB
    const int tid = threadIdx.x;
    const int lane = tid & 63;
    const int wid = tid >> 6;
    const int wm = wid >> 2, wn = wid & 3;   // 2(M) x 4(N); wave tile 128x64
    const int arow = lane & 15;
    const int g = lane >> 4;
    const int srow = tid >> 3;               // 0..63
    const int schunk = tid & 7;
    const int csw = schunk ^ (srow & 7);     // inverse swizzle on SOURCE (involution)
    const int K = 768;

    // T1: XCD-chunked bijective swizzle (m204); NBN=3
    const int nwg = gridDim.x;
    const int q_ = nwg >> 3, r_ = nwg & 7;
    const int xcd = blockIdx.x & 7, off = blockIdx.x >> 3;
    const int swz = (xcd < r_ ? xcd*(q_+1) : r_*(q_+1) + (xcd - r_)*q_) + off;
    const long bn = swz % 3, bm = swz / 3;

    f32x4 acc[8][4];
#pragma unroll
    for (int i = 0; i < 8; ++i)
#pragma unroll
        for (int j = 0; j < 4; ++j) acc[i][j] = (f32x4){0.f,0.f,0.f,0.f};

    const bf16* Ab = A + (bm*256 + srow)*(long)K + csw*8;
    const bf16* Bb = B + (bn*256 + srow)*(long)K + csw*8;

    auto issueA = [&](int buf, int kt, int s) {
        __builtin_amdgcn_global_load_lds(GPTR(Ab + (long)(s*64)*K + kt*64),
            LPTR(sh + buf*32768 + s*4096 + tid*8), 16, 0, 0);
    };
    auto issueB = [&](int buf, int kt, int s) {
        __builtin_amdgcn_global_load_lds(GPTR(Bb + (long)(s*64)*K + kt*64),
            LPTR(sh + buf*32768 + 16384 + s*4096 + tid*8), 16, 0, 0);
    };
    auto phase = [&](int buf, int qm, int qn) {
        const bf16* ldsA = sh + buf*32768;
        const bf16* ldsB = sh + buf*32768 + 16384;
        bf16x8 af[4][2], bfr[2][2];
#pragma unroll
        for (int i = 0; i < 4; ++i) {
            int R = wm*128 + (qm*4 + i)*16 + arow;
#pragma unroll
            for (int kk = 0; kk < 2; ++kk)
                af[i][kk] = *(const bf16x8*)&ldsA[R*64 + (((kk*4 + g) ^ (R & 7))*8)];
        }
#pragma unroll
        for (int j = 0; j < 2; ++j) {
            int R = wn*64 + (qn*2 + j)*16 + arow;
#pragma unroll
            for (int kk = 0; kk < 2; ++kk)
                bfr[j][kk] = *(const bf16x8*)&ldsB[R*64 + (((kk*4 + g) ^ (R & 7))*8)];
        }
        asm volatile("s_waitcnt lgkmcnt(0)" ::: "memory");
        __builtin_amdgcn_sched_barrier(0);
        __builtin_amdgcn_s_setprio(1);
#pragma unroll
        for (int i = 0; i < 4; ++i)
#pragma unroll
            for (int j = 0; j < 2; ++j)
#pragma unroll
                for (int kk = 0; kk < 2; ++kk)
                    acc[qm*4 + i][qn*2 + j] = __builtin_amdgcn_mfma_f32_16x16x32_bf16(
                        af[i][kk], bfr[j][kk], acc[qm*4 + i][qn*2 + j], 0, 0, 0);
        __builtin_amdgcn_s_setprio(0);
        __builtin_amdgcn_sched_barrier(0);
    };

    const int nkt = K / 64;   // 12
    // prologue: stage tile 0 into buf 0
#pragma unroll
    for (int s = 0; s < 4; ++s) { issueA(0, 0, s); issueB(0, 0, s); }

    for (int kt = 0; kt < nkt; ++kt) {
        const int cur = kt & 1, nxt = cur ^ 1;
        const bool pre = (kt + 1 < nkt);
        if (pre) { issueA(nxt, kt+1, 0); issueA(nxt, kt+1, 1); }
        if (pre) asm volatile("s_waitcnt vmcnt(2)" ::: "memory");   // drain tile kt's 8
        else     asm volatile("s_waitcnt vmcnt(0)" ::: "memory");
        __builtin_amdgcn_s_barrier();          // everyone's stage of tile kt visible
        phase(cur, 0, 0);
        if (pre) { issueA(nxt, kt+1, 2); issueA(nxt, kt+1, 3); }
        phase(cur, 0, 1);
        if (pre) { issueB(nxt, kt+1, 0); issueB(nxt, kt+1, 1); }
        phase(cur, 1, 0);
        if (pre) { issueB(nxt, kt+1, 2); issueB(nxt, kt+1, 3); }
        phase(cur, 1, 1);
        __builtin_amdgcn_s_barrier();          // all reads of buf cur retired
    }

    // ---------------- epilogue: LDS transpose in 2 M-halves, bf16x8 stores ----------
    bf16* tls = sh;                   // 128 x 264 bf16 = 67.6 KB
#pragma unroll 1
    for (int half = 0; half < 2; ++half) {
        __syncthreads();
        if (wm == half) {
#pragma unroll
            for (int mf = 0; mf < 8; ++mf) {
                int rowl = mf*16 + (g << 2);
#pragma unroll
                for (int nf = 0; nf < 4; ++nf) {
                    int coll = wn*64 + nf*16 + arow;
                    float bcol = bias[bn*256 + coll];
#pragma unroll
                    for (int r = 0; r < 4; ++r)
                        tls[(rowl + r)*264 + coll] = (bf16)fast_gelu(acc[mf][nf][r] + bcol);
                }
            }
        }
        __syncthreads();
#pragma unroll
        for (int it = 0; it < 8; ++it) {
            int idx = it*512 + tid;           // 0..4095
            int mloc = idx >> 5;              // 0..127
            int ck = idx & 31;                // 16B chunk within 256 cols
            bf16x8 v = *(const bf16x8*)&tls[mloc*264 + ck*8];
            int m = (int)bm*256 + half*128 + mloc;
            int col = (int)bn*256 + ck*8;
            int nh = col / HD;
            int c = col - nh*HD;
            int bflag = m >= L0;
            int l = m - (bflag ? L0 : 0);
            size_t addr = ((size_t)(bflag*8 + nh)*L0 + l)*HD + c;
            *(bf16x8*)&Out[addr] = v;
        }
    }
}

// ---------------- 128x128 MFMA GEMM (R8 structure) — kv-compact & proj --------------
// MODE 1: proj. fp32 out[m*N+n].
// MODE 2: kv-compact. A rows GATHERED; N=1536; GELU; compact [part][b*8+nh][3200][96].
template<int MODE>
__global__ __launch_bounds__(256) void gemm_bt(
    const bf16* __restrict__ A, const bf16* __restrict__ B,
    const float* __restrict__ bias, void* __restrict__ Out,
    int M, int N, int K, int NBN)
{
    __shared__ bf16 sh[2*16384];
    const int tid = threadIdx.x;
    const int lane = tid & 63;
    const int w = tid >> 6;
    const int wr = w >> 1, wc = w & 1;

    const int nwg = gridDim.x;
    const int q_ = nwg >> 3, r_ = nwg & 7;
    const int xcd = blockIdx.x & 7, off = blockIdx.x >> 3;
    const int swz = (xcd < r_ ? xcd*(q_+1) : r_*(q_+1) + (xcd - r_)*q_) + off;
    const long bn = swz % NBN, bm = swz / NBN;

    f32x4 acc[4][4];
#pragma unroll
    for (int i = 0; i < 4; ++i)
#pragma unroll
        for (int j = 0; j < 4; ++j) acc[i][j] = (f32x4){0.f,0.f,0.f,0.f};

    const int trow = tid >> 3;
    const int tchunk = (tid & 7) ^ (trow & 7);

    long aoff[4];
#pragma unroll
    for (int s = 0; s < 4; ++s) {
        int rA = (int)bm*128 + s*32 + trow;
        if (MODE == 2) {
            int b = rA / 3200; int r = rA - b*3200;
            int t = r / 400;  int rr = r - t*400;
            int yi = rr / NYC, xi = rr - yi*NYC;
            int y = cmap(yi), x = cmap(xi);
            aoff[s] = ((long)b*L0 + (t*H0 + y)*W0 + x) * (long)K;
        } else {
            aoff[s] = (long)rA * K;
        }
    }
    const bf16* Bg = B + (bn*128 + trow)*(long)K + tchunk*8;

    const int arow = lane & 15;
    const int g8 = (lane >> 4) * 8;
    const int aswz = (arow & 7) * 8;

    auto stage = [&](int buf, int kt) {
        bf16* ldsA = sh + buf*16384;
        bf16* ldsB = sh + buf*16384 + 8192;
#pragma unroll
        for (int s = 0; s < 4; ++s) {
            __builtin_amdgcn_global_load_lds(GPTR(A + aoff[s] + kt*64 + tchunk*8),
                                             LPTR(ldsA + s*2048 + tid*8), 16, 0, 0);
            __builtin_amdgcn_global_load_lds(GPTR(Bg + (long)kt*64 + (long)s*32*K),
                                             LPTR(ldsB + s*2048 + tid*8), 16, 0, 0);
        }
    };
    auto compute = [&](int buf) {
        const bf16* ldsA = sh + buf*16384;
        const bf16* ldsB = sh + buf*16384 + 8192;
#pragma unroll
        for (int kk = 0; kk < 2; ++kk) {
            bf16x8 af[4], bfr[4];
#pragma unroll
            for (int i = 0; i < 4; ++i)
                af[i] = *(const bf16x8*)&ldsA[(wr*64 + i*16 + arow)*64 + ((kk*32 + g8) ^ aswz)];
#pragma unroll
            for (int j = 0; j < 4; ++j)
                bfr[j] = *(const bf16x8*)&ldsB[(wc*64 + j*16 + arow)*64 + ((kk*32 + g8) ^ aswz)];
            __builtin_amdgcn_s_setprio(1);
#pragma unroll
            for (int i = 0; i < 4; ++i)
#pragma unroll
                for (int j = 0; j < 4; ++j)
                    acc[i][j] = __builtin_amdgcn_mfma_f32_16x16x32_bf16(af[i], bfr[j], acc[i][j], 0, 0, 0);
            __builtin_amdgcn_s_setprio(0);
        }
    };

    const int nkt = K / 64;
    stage(0, 0);
    for (int kt = 0; kt < nkt; ++kt) {
        if (kt + 1 < nkt) {
            stage((kt + 1) & 1, kt + 1);
            asm volatile("s_waitcnt vmcnt(8)" ::: "memory");
        } else {
            asm volatile("s_waitcnt vmcnt(0)" ::: "memory");
        }
        __builtin_amdgcn_s_barrier();
        __builtin_amdgcn_sched_barrier(0);
        compute(kt & 1);
        __builtin_amdgcn_sched_barrier(0);
        __builtin_amdgcn_s_barrier();
    }

    if (MODE == 1) {
#pragma unroll
        for (int j = 0; j < 4; ++j) {
            const int col = (int)bn*128 + wc*64 + j*16 + (lane & 15);
            const float bcol = bias[col];
#pragma unroll
            for (int i = 0; i < 4; ++i) {
                int row0 = (int)bm*128 + wr*64 + i*16 + ((lane>>4)<<2);
#pragma unroll
                for (int r = 0; r < 4; ++r)
                    ((float*)Out)[(size_t)(row0 + r)*N + col] = acc[i][j][r] + bcol;
            }
        }
    } else {
        bf16* tls = sh;
#pragma unroll
        for (int j = 0; j < 4; ++j) {
            const int colb = (int)bn*128 + wc*64 + j*16;
            const int lcol = wc*64 + j*16 + (lane & 15);
            const float bcol = bias[colb + (lane & 15)];
#pragma unroll
            for (int i = 0; i < 4; ++i) {
                int lrow0 = wr*64 + i*16 + ((lane>>4)<<2);
#pragma unroll
                for (int r = 0; r < 4; ++r)
                    tls[(lrow0 + r)*136 + lcol] = (bf16)fast_gelu(acc[i][j][r] + bcol);
            }
        }
        __syncthreads();
#pragma unroll
        for (int it = 0; it < 8; ++it) {
            int idx = it*256 + tid;
            int mloc = idx >> 4;
            int ck = idx & 15;
            bf16x8 v = *(const bf16x8*)&tls[mloc*136 + ck*8];
            int m = (int)bm*128 + mloc;
            int col = (int)bn*128 + ck*8;
            int part = col / 768;
            int cb = col - part*768;
            int nh = cb / HD;
            int c = cb - nh*HD;
            int b = m / 3200; int r = m - b*3200;
            size_t addr = ((size_t)(part*16 + b*8 + nh)*3200 + r)*HD + c;
            *(bf16x8*)&((bf16*)Out)[addr] = v;
        }
    }
}

// ---------------- depthwise conv3d q-path (k=3, pad=1, stride (1,2,2)), bf16 out ----
__global__ __launch_bounds__(256) void dwconv_q(
    const bf16* __restrict__ in, const float* __restrict__ w,
    bf16* __restrict__ out, int total)
{
    __shared__ float lw[27*HD];
    for (int i = threadIdx.x; i < 27*HD; i += 256) {
        int c = i / 27, tap = i % 27;
        lw[tap*HD + c] = w[i];
    }
    __syncthreads();
    int idx = blockIdx.x*256 + threadIdx.x;
    if (idx >= total) return;
    int c8 = idx % 12;
    int p = idx / 12;
    int xo = p % WP_Q;
    int yo = (p / WP_Q) % HP_Q;
    int bh = p / (WP_Q*HP_Q);
    const bf16* ip = in + (size_t)bh * L0 * HD + c8*8;

    float acc[T0][8];
#pragma unroll
    for (int t = 0; t < T0; ++t)
#pragma unroll
        for (int j = 0; j < 8; ++j) acc[t][j] = 0.f;

#pragma unroll
    for (int dy = 0; dy < 3; ++dy) {
        int y = yo*2 + dy - 1;
        if ((unsigned)y >= (unsigned)H0) continue;
#pragma unroll
        for (int dx = 0; dx < 3; ++dx) {
            int x = xo*2 + dx - 1;
            if ((unsigned)x >= (unsigned)W0) continue;
            float wreg[3][8];
#pragma unroll
            for (int dt = 0; dt < 3; ++dt)
#pragma unroll
                for (int j = 0; j < 8; ++j)
                    wreg[dt][j] = lw[(dt*9 + dy*3 + dx)*HD + c8*8 + j];
            const bf16* colp = ip + ((size_t)(y*W0 + x))*HD;
#pragma unroll
            for (int t = 0; t < T0; ++t) {
                bf16x8 v = *(const bf16x8*)(colp + (size_t)t*H0*W0*HD);
                float f[8];
#pragma unroll
                for (int j = 0; j < 8; ++j) f[j] = (float)v[j];
#pragma unroll
                for (int dt = 0; dt < 3; ++dt) {
                    int to = t - dt + 1;
                    if (to < 0 || to >= T0) continue;
#pragma unroll
                    for (int j = 0; j < 8; ++j)
                        acc[to][j] += wreg[dt][j] * f[j];
                }
            }
        }
    }

#pragma unroll
    for (int to = 0; to < T0; ++to) {
        int l = (to*HP_Q + yo)*WP_Q + xo;
        bf16x8 ov;
#pragma unroll
        for (int j = 0; j < 8; ++j) ov[j] = (bf16)acc[to][j];
        *(bf16x8*)&out[((size_t)bh*LQ + l)*HD + c8*8] = ov;
    }
}

// ---------------- merged K+V conv from compact input, pad-zeroing folded in --------
// seg 0 (blocks 0..39):  k -> kout[bh][l][c], rows 392..415 zeroed by blocks 37..39
// seg 1 (blocks 40..79): v -> vtout[bh][c][l] transposed, cols 392..415 zeroed
__global__ __launch_bounds__(256) void dwconv_kv_all(
    const bf16* __restrict__ kv, const float* __restrict__ wk,
    const float* __restrict__ wv, bf16* __restrict__ kout, bf16* __restrict__ vtout)
{
    const int seg = blockIdx.x / 40;
    const int lb  = blockIdx.x % 40;
    const float* w = seg ? wv : wk;
    const bf16* in = kv + (size_t)seg * 16 * 3200 * HD;
    __shared__ float lw[27*HD];
    for (int i = threadIdx.x; i < 27*HD; i += 256) {
        int c = i / 27, tap = i % 27;
        lw[tap*HD + c] = w[i];
    }
    __syncthreads();

    if (lb >= 37) {   // pad-zero blocks (768 threads per seg, 36864 elems)
        int pid = (lb - 37)*256 + threadIdx.x;
        if (seg == 0) {
            for (int e = pid; e < 16*24*96; e += 768) {
                int bh = e / (24*96); int rem = e - bh*24*96;
                int l = LK + rem / 96; int c = rem % 96;
                kout[((size_t)bh*LKP + l)*HD + c] = (bf16)0.f;
            }
        } else {
            for (int e = pid; e < 16*96*24; e += 768) {
                int bh = e / (96*24); int rem = e - bh*96*24;
                int c = rem / 24; int l = LK + rem % 24;
                vtout[((size_t)bh*HD + c)*LKP + l] = (bf16)0.f;
            }
        }
        return;
    }

    int idx = lb*256 + threadIdx.x;
    if (idx >= 16*HP_K*WP_K*12) return;
    int c8 = idx % 12;
    int p = idx / 12;
    int xo = p % WP_K;
    int yo = (p / WP_K) % HP_K;
    int bh = p / (WP_K*HP_K);
    const bf16* ip = in + (size_t)bh * 3200 * HD + c8*8;

    float acc[T0][8];
#pragma unroll
    for (int t = 0; t < T0; ++t)
#pragma unroll
        for (int j = 0; j < 8; ++j) acc[t][j] = 0.f;

#pragma unroll
    for (int dy = 0; dy < 3; ++dy) {
        int yi = 3*yo + dy - 1;
        if ((unsigned)yi >= (unsigned)NYC) continue;
#pragma unroll
        for (int dx = 0; dx < 3; ++dx) {
            int xi = 3*xo + dx - 1;
            if ((unsigned)xi >= (unsigned)NYC) continue;
            float wreg[3][8];
#pragma unroll
            for (int dt = 0; dt < 3; ++dt)
#pragma unroll
                for (int j = 0; j < 8; ++j)
                    wreg[dt][j] = lw[(dt*9 + dy*3 + dx)*HD + c8*8 + j];
            const bf16* colp = ip + ((size_t)(yi*NYC + xi))*HD;
#pragma unroll
            for (int t = 0; t < T0; ++t) {
                bf16x8 v = *(const bf16x8*)(colp + (size_t)t*400*HD);
                float f[8];
#pragma unroll
                for (int j = 0; j < 8; ++j) f[j] = (float)v[j];
#pragma unroll
                for (int dt = 0; dt < 3; ++dt) {
                    int to = t - dt + 1;
                    if (to < 0 || to >= T0) continue;
#pragma unroll
                    for (int j = 0; j < 8; ++j)
                        acc[to][j] += wreg[dt][j] * f[j];
                }
            }
        }
    }

#pragma unroll
    for (int to = 0; to < T0; ++to) {
        int l = (to*HP_K + yo)*WP_K + xo;
        if (seg == 1) {
#pragma unroll
            for (int j = 0; j < 8; ++j)
                vtout[((size_t)bh*HD + c8*8 + j)*LKP + l] = (bf16)acc[to][j];
        } else {
            bf16x8 ov;
#pragma unroll
            for (int j = 0; j < 8; ++j) ov[j] = (bf16)acc[to][j];
            *(bf16x8*)&kout[((size_t)bh*LKP + l)*HD + c8*8] = ov;
        }
    }
}

// ---------------- MFMA attention: block = (b,h) x 64 q rows, wave = 16 q rows -------
__global__ __launch_bounds__(256) void attn_mfma(
    const bf16* __restrict__ q, const bf16* __restrict__ k,
    const bf16* __restrict__ vt, bf16* __restrict__ out)
{
    const int tid = threadIdx.x;
    const int lane = tid & 63;
    const int w = tid >> 6;
    const int col = lane & 15;
    const int g = lane >> 4;
    const int blk = blockIdx.x;
    const int qblk = blk % (LQ/64);
    const int bh = blk / (LQ/64);
    const int q0 = qblk*64 + w*16;

    const bf16* Qp  = q  + ((size_t)bh*LQ + q0)*HD;
    const bf16* Kp  = k  + (size_t)bh*LKP*HD;
    const bf16* VTp = vt + (size_t)bh*HD*LKP;

    bf16x8 qf[3];
#pragma unroll
    for (int c = 0; c < 3; ++c)
        qf[c] = *(const bf16x8*)&Qp[(size_t)col*HD + c*32 + g*8];

    f32x4 o[6];
#pragma unroll
    for (int t = 0; t < 6; ++t) o[t] = (f32x4){0.f,0.f,0.f,0.f};
    float lsum = 0.f;

    for (int kc = 0; kc < LKP/32; ++kc) {
        const int kvb = kc*32;
        uint32_t P[2][2];
#pragma unroll
        for (int s = 0; s < 2; ++s) {
            f32x4 acc = (f32x4){0.f,0.f,0.f,0.f};
#pragma unroll
            for (int c = 0; c < 3; ++c) {
                bf16x8 kf = *(const bf16x8*)&Kp[(size_t)(kvb + s*16 + col)*HD + c*32 + g*8];
                acc = __builtin_amdgcn_mfma_f32_16x16x32_bf16(kf, qf[c], acc, 0, 0, 0);
            }
            bf16x4 pb;
#pragma unroll
            for (int r = 0; r < 4; ++r) {
                int kv = kvb + s*16 + g*4 + r;
                float p = (kv < LK) ? __expf(acc[r]*SCALE) : 0.f;
                lsum += p;
                pb[r] = (bf16)p;
            }
            union { bf16x4 v; uint32_t u[2]; } pk; pk.v = pb;
            P[s][0] = pk.u[0]; P[s][1] = pk.u[1];
        }
        uint32_t sa0 = (g < 2) ? P[1][0] : P[0][0];
        uint32_t sa1 = (g < 2) ? P[1][1] : P[0][1];
        uint32_t tb0 = (g < 2) ? P[0][0] : P[1][0];
        uint32_t tb1 = (g < 2) ? P[0][1] : P[1][1];
        uint32_t R32_0 = (uint32_t)__shfl_xor((int)sa0, 32);
        uint32_t R32_1 = (uint32_t)__shfl_xor((int)sa1, 32);
        uint32_t R48_0 = (uint32_t)__shfl_xor((int)sa0, 48);
        uint32_t R48_1 = (uint32_t)__shfl_xor((int)sa1, 48);
        uint32_t R16_0 = (uint32_t)__shfl_xor((int)tb0, 16);
        uint32_t R16_1 = (uint32_t)__shfl_xor((int)tb1, 16);
        union { uint32_t u[4]; bf16x8 v; } pf;
        pf.u[0] = (g == 0) ? P[0][0] : (g == 1) ? R48_0 : (g == 2) ? R32_0 : R16_0;
        pf.u[1] = (g == 0) ? P[0][1] : (g == 1) ? R48_1 : (g == 2) ? R32_1 : R16_1;
        pf.u[2] = (g == 0) ? R16_0 : (g == 1) ? R32_0 : (g == 2) ? R48_0 : P[1][0];
        pf.u[3] = (g == 0) ? R16_1 : (g == 1) ? R32_1 : (g == 2) ? R48_1 : P[1][1];
#pragma unroll
        for (int t = 0; t < 6; ++t) {
            bf16x8 vf = *(const bf16x8*)&VTp[(size_t)(t*16 + col)*LKP + kvb + g*8];
            o[t] = __builtin_amdgcn_mfma_f32_16x16x32_bf16(vf, pf.v, o[t], 0, 0, 0);
        }
    }

    lsum += __shfl_xor(lsum, 16);
    lsum += __shfl_xor(lsum, 32);
    float inv = 1.f / lsum;

    const int b = bh >> 3, nh = bh & 7;
    size_t obase = ((size_t)b*LQ + q0 + col)*CDIM + (size_t)nh*HD;
#pragma unroll
    for (int t = 0; t < 6; ++t) {
        bf16x4 qres = *(const bf16x4*)&Qp[(size_t)col*HD + t*16 + g*4];
        bf16x4 ov;
#pragma unroll
        for (int r = 0; r < 4; ++r)
            ov[r] = (bf16)(o[t][r]*inv + (float)qres[r]);
        *(bf16x4*)&out[obase + t*16 + g*4] = ov;
    }
}

extern "C" void kernel_launch(void* const* d_in, const int* in_sizes, int n_in,
                              void* d_out, int out_size, void* d_ws, size_t ws_size,
                              hipStream_t stream) {
    const float* x      = (const float*)d_in[0];
    const float* qkv_w  = (const float*)d_in[1];
    const float* qkv_b  = (const float*)d_in[2];
    const float* proj_w = (const float*)d_in[3];
    const float* proj_b = (const float*)d_in[4];
    const float* pq_w   = (const float*)d_in[5];
    const float* pk_w   = (const float*)d_in[6];
    const float* pv_w   = (const float*)d_in[7];

    uint8_t* ws = (uint8_t*)d_ws;
    bf16* x_bf     = (bf16*)(ws);                  // 77,070,336 B
    bf16* qg_out   = (bf16*)(ws +  77070336);      // 77,070,336 B  [16][L0][96] (GELU'd Q)
    bf16* kv_c     = (bf16*)(ws + 154140672);      // 19,660,800 B  [2][16][3200][96]
    bf16* wqkv_bf  = (bf16*)(ws + 173801472);      // 3,538,944 B
    bf16* wproj_bf = (bf16*)(ws + 177340416);      // 1,179,648 B
    bf16* q_bf     = (bf16*)(ws + 178520064);      // 19,267,584 B  [16][6272][96]
    bf16* k_bf     = (bf16*)(ws + 197787648);      // 1,277,952 B   [16][416][96]
    bf16* vt_bf    = (bf16*)(ws + 199065600);      // 1,277,952 B   [16][96][416]
    bf16* attn_o   = (bf16*)(ws + 200343552);      // 19,267,584 B -> end 219,611,136

    cvt_all<<<2560, 256, 0, stream>>>((const f4*)x, (const f4*)qkv_w, (const f4*)proj_w,
                                      (bf16x4*)x_bf, (bf16x4*)wqkv_bf, (bf16x4*)wproj_bf);

    // Q-part GEMM: 256^2 4-phase counted-vmcnt. M=50176 (196 bm), N=768 (3 bn).
    gemm256_q<<<196*3, 512, 0, stream>>>(x_bf, wqkv_bf, qkv_b, qg_out);

    // K/V compact GEMM: M=6400 gathered rows, N=1536, GELU, compact store
    gemm_bt<2><<<50*12, 256, 0, stream>>>(
        x_bf, wqkv_bf + (size_t)768*768, qkv_b + 768, kv_c, MKV, 1536, 768, 12);

    dwconv_q<<<588, 256, 0, stream>>>(qg_out, pq_w, q_bf, 16*HP_Q*WP_Q*12);
    dwconv_kv_all<<<80, 256, 0, stream>>>(kv_c, pk_w, pv_w, k_bf, vt_bf);

    attn_mfma<<<16*(LQ/64), 256, 0, stream>>>(q_bf, k_bf, vt_bf, attn_o);

    gemm_bt<1><<<6*98, 256, 0, stream>>>(
        attn_o, wproj_bf, proj_b, d_out, 12544, 768, 768, 6);
}

// Round 10
// 314.622 us; speedup vs baseline: 1.6098x; 1.0370x over previous
//
#include <hip/hip_runtime.h>
#include <cstdint>

#define NH 8
#define HD 96
#define CDIM 768
#define BQ 2
#define T0 8
#define H0 56
#define W0 56
#define L0 (T0*H0*W0)     // 25088
#define HP_Q 28
#define WP_Q 28
#define LQ (T0*HP_Q*WP_Q) // 6272
#define HP_K 7
#define WP_K 7
#define LK (T0*HP_K*WP_K) // 392
#define LKP 416           // kv padded to multiple of 32
#define SCALE 0.10206207261596577f
#define NYC 20
#define MKV 6400          // 2*8*400 gathered kv rows (50 x 128)

typedef __bf16 bf16;
typedef bf16 bf16x4 __attribute__((ext_vector_type(4)));
typedef bf16 bf16x8 __attribute__((ext_vector_type(8)));
typedef float f32x4 __attribute__((ext_vector_type(4)));
typedef float f4 __attribute__((ext_vector_type(4)));

#define GPTR(x) ((const __attribute__((address_space(1))) void*)(x))
#define LPTR(x) ((__attribute__((address_space(3))) void*)(x))

// fast erf-GELU: A&S 7.1.27 rational erf approx, |err(erf)| <= 5e-4 (<< bf16 rounding)
__device__ __forceinline__ float fast_gelu(float x) {
    float z = __builtin_fabsf(x) * 0.7071067811865476f;
    float p = 1.f + z*(0.278393f + z*(0.230389f + z*(0.000972f + z*0.078108f)));
    p = p * p;
    p = p * p;
    float e = 1.f - __builtin_amdgcn_rcpf(p);   // erf(|x|/sqrt2)
    float erfv = (x < 0.f) ? -e : e;
    return 0.5f * x * (1.f + erfv);
}

// ---------------- weight fp32 -> bf16 (x stays fp32; GEMMs consume it directly) ----
#define NW4 442368
#define NP4 147456
__global__ void cvt_w(const f4* __restrict__ wq, const f4* __restrict__ wp,
                      bf16x4* __restrict__ wqo, bf16x4* __restrict__ wpo) {
    const long total = NW4 + NP4;
    long stride = (long)gridDim.x * blockDim.x;
    for (long i = (long)blockIdx.x * blockDim.x + threadIdx.x; i < total; i += stride) {
        f4 v; bf16x4* o;
        if (i < NW4) { v = wq[i]; o = wqo + i; }
        else         { v = wp[i - NW4]; o = wpo + (i - NW4); }
        bf16x4 t;
        t[0] = (bf16)v[0]; t[1] = (bf16)v[1]; t[2] = (bf16)v[2]; t[3] = (bf16)v[3];
        *o = t;
    }
}

// map compact grid index (0..19) -> original spatial coord (y or x)
__device__ __forceinline__ int cmap(int i) {
    return ((i + 1) / 3) * 8 + (i + 1) % 3 - 1;
}

// ======== 128x128 MFMA GEMM with fp32 A staged direct from input (no pre-cvt) ======
// BK=32 dbuf: per buf A-f32 16KB + B-bf16 8KB = 24KB; 2 bufs = 48KB -> 3 blocks/CU.
// A staged via global_load_lds (16B=4 floats), cvt to bf16 at ds_read time.
// Swizzles: A (128B rows, 8 chunks): chunk ^= row&7  [proven R8 pattern];
//           B (64B rows, 4 chunks):  chunk ^= (row>>1)&3.
// MODE 0: Q-part. N=768, GELU, scatter bf16 [16][L0][96].
// MODE 2: kv-compact. A rows GATHERED from 400 touched tokens; N=1536; GELU;
//         compact store [part][b*8+nh][t*400+rr][96].
template<int MODE>
__global__ __launch_bounds__(256) void gemm_f32a(
    const float* __restrict__ A, const bf16* __restrict__ B,
    const float* __restrict__ bias, bf16* __restrict__ Out,
    int M, int N, int K, int NBN)
{
    __shared__ uint8_t sh[2*24576];
    const int tid = threadIdx.x;
    const int lane = tid & 63;
    const int w = tid >> 6;
    const int wr = w >> 1, wc = w & 1;
    const int g = lane >> 4;
    const int ar = lane & 15;

    // T1: XCD-chunked bijective swizzle (m204)
    const int nwg = gridDim.x;
    const int q_ = nwg >> 3, r_ = nwg & 7;
    const int xcd = blockIdx.x & 7, off = blockIdx.x >> 3;
    const int swz = (xcd < r_ ? xcd*(q_+1) : r_*(q_+1) + (xcd - r_)*q_) + off;
    const long bn = swz % NBN, bm = swz / NBN;

    f32x4 acc[4][4];
#pragma unroll
    for (int i = 0; i < 4; ++i)
#pragma unroll
        for (int j = 0; j < 4; ++j) acc[i][j] = (f32x4){0.f,0.f,0.f,0.f};

    // A staging: 4 rounds x 32 rows; thread covers (row = s*32 + t>>3, lds slot t&7)
    const int arow_s = tid >> 3;                     // 0..31
    const int csa = (tid & 7) ^ (arow_s & 7);        // inverse swizzle on SOURCE
    long aoff[4];
#pragma unroll
    for (int s = 0; s < 4; ++s) {
        int rA = (int)bm*128 + s*32 + arow_s;
        if (MODE == 2) {
            int b = rA / 3200; int r = rA - b*3200;
            int t = r / 400;  int rr = r - t*400;
            int yi = rr / NYC, xi = rr - yi*NYC;
            aoff[s] = ((long)b*L0 + (t*H0 + cmap(yi))*W0 + cmap(xi)) * (long)K;
        } else {
            aoff[s] = (long)rA * K;
        }
    }
    // B staging: 2 rounds x 64 rows; thread covers (row = s*64 + t>>2, lds slot t&3)
    const int brow_s = tid >> 2;                     // 0..63
    const int csb = (tid & 3) ^ ((tid >> 3) & 3);    // = slot ^ ((row>>1)&3)
    const bf16* Bg = B + (bn*128 + brow_s)*(long)K + csb*8;

    auto stage = [&](int buf, int kt) {
        uint8_t* base = sh + buf*24576;
#pragma unroll
        for (int s = 0; s < 4; ++s)
            __builtin_amdgcn_global_load_lds(GPTR(A + aoff[s] + kt*32 + csa*4),
                LPTR(base + s*4096 + tid*16), 16, 0, 0);
#pragma unroll
        for (int s = 0; s < 2; ++s)
            __builtin_amdgcn_global_load_lds(GPTR(Bg + (long)kt*32 + (long)s*64*K),
                LPTR(base + 16384 + s*4096 + tid*16), 16, 0, 0);
    };
    auto compute = [&](int buf) {
        const float* ldsA = (const float*)(sh + buf*24576);
        const bf16* ldsB = (const bf16*)(sh + buf*24576 + 16384);
        bf16x8 af[4], bfr[4];
#pragma unroll
        for (int i = 0; i < 4; ++i) {
            int R = wr*64 + i*16 + ar;
            f32x4 lo = *(const f32x4*)&ldsA[R*32 + (((2*g    ) ^ (R & 7))*4)];
            f32x4 hi = *(const f32x4*)&ldsA[R*32 + (((2*g + 1) ^ (R & 7))*4)];
            bf16x8 t;
            t[0] = (bf16)lo[0]; t[1] = (bf16)lo[1]; t[2] = (bf16)lo[2]; t[3] = (bf16)lo[3];
            t[4] = (bf16)hi[0]; t[5] = (bf16)hi[1]; t[6] = (bf16)hi[2]; t[7] = (bf16)hi[3];
            af[i] = t;
        }
#pragma unroll
        for (int j = 0; j < 4; ++j) {
            int R = wc*64 + j*16 + ar;
            bfr[j] = *(const bf16x8*)&ldsB[R*32 + ((g ^ ((R >> 1) & 3))*8)];
        }
        __builtin_amdgcn_s_setprio(1);
#pragma unroll
        for (int i = 0; i < 4; ++i)
#pragma unroll
            for (int j = 0; j < 4; ++j)
                acc[i][j] = __builtin_amdgcn_mfma_f32_16x16x32_bf16(af[i], bfr[j], acc[i][j], 0, 0, 0);
        __builtin_amdgcn_s_setprio(0);
    };

    const int nkt = K / 32;   // 24
    stage(0, 0);
    for (int kt = 0; kt < nkt; ++kt) {
        if (kt + 1 < nkt) {
            stage((kt + 1) & 1, kt + 1);
            asm volatile("s_waitcnt vmcnt(6)" ::: "memory");   // kt's 6 loads landed
        } else {
            asm volatile("s_waitcnt vmcnt(0)" ::: "memory");
        }
        __builtin_amdgcn_s_barrier();
        __builtin_amdgcn_sched_barrier(0);
        compute(kt & 1);
        __builtin_amdgcn_sched_barrier(0);
        __builtin_amdgcn_s_barrier();
    }

    // ---------------- epilogue: LDS transpose + GELU + coalesced bf16x8 stores ------
    bf16* tls = (bf16*)sh;                 // 128 x 136 bf16 = 34.8 KB
#pragma unroll
    for (int j = 0; j < 4; ++j) {
        const int colb = (int)bn*128 + wc*64 + j*16;
        const int lcol = wc*64 + j*16 + ar;
        const float bcol = bias[colb + ar];
#pragma unroll
        for (int i = 0; i < 4; ++i) {
            int lrow0 = wr*64 + i*16 + (g << 2);
#pragma unroll
            for (int r = 0; r < 4; ++r)
                tls[(lrow0 + r)*136 + lcol] = (bf16)fast_gelu(acc[i][j][r] + bcol);
        }
    }
    __syncthreads();
#pragma unroll
    for (int it = 0; it < 8; ++it) {
        int idx = it*256 + tid;
        int mloc = idx >> 4;
        int ck = idx & 15;
        bf16x8 v = *(const bf16x8*)&tls[mloc*136 + ck*8];
        int m = (int)bm*128 + mloc;
        int col = (int)bn*128 + ck*8;
        if (MODE == 0) {
            int nh = col / HD;
            int c = col - nh*HD;
            int bflag = m >= L0;              // M = 2*L0
            int l = m - (bflag ? L0 : 0);
            size_t addr = ((size_t)(bflag*8 + nh)*L0 + l)*HD + c;
            *(bf16x8*)&Out[addr] = v;
        } else {
            int part = col / 768;
            int cb = col - part*768;
            int nh = cb / HD;
            int c = cb - nh*HD;
            int b = m / 3200; int r = m - b*3200;   // r = t*400 + rr
            size_t addr = ((size_t)(part*16 + b*8 + nh)*3200 + r)*HD + c;
            *(bf16x8*)&Out[addr] = v;
        }
    }
}

// ---------------- 128x128 bf16-A GEMM (R8 structure) — proj only --------------------
__global__ __launch_bounds__(256) void gemm_proj(
    const bf16* __restrict__ A, const bf16* __restrict__ B,
    const float* __restrict__ bias, float* __restrict__ Out,
    int M, int N, int K, int NBN)
{
    __shared__ bf16 sh[2*16384];
    const int tid = threadIdx.x;
    const int lane = tid & 63;
    const int w = tid >> 6;
    const int wr = w >> 1, wc = w & 1;

    const int nwg = gridDim.x;
    const int q_ = nwg >> 3, r_ = nwg & 7;
    const int xcd = blockIdx.x & 7, off = blockIdx.x >> 3;
    const int swz = (xcd < r_ ? xcd*(q_+1) : r_*(q_+1) + (xcd - r_)*q_) + off;
    const long bn = swz % NBN, bm = swz / NBN;

    f32x4 acc[4][4];
#pragma unroll
    for (int i = 0; i < 4; ++i)
#pragma unroll
        for (int j = 0; j < 4; ++j) acc[i][j] = (f32x4){0.f,0.f,0.f,0.f};

    const int trow = tid >> 3;
    const int tchunk = (tid & 7) ^ (trow & 7);
    const bf16* Ag = A + (bm*128 + trow)*(long)K + tchunk*8;
    const bf16* Bg = B + (bn*128 + trow)*(long)K + tchunk*8;

    const int arow = lane & 15;
    const int g8 = (lane >> 4) * 8;
    const int aswz = (arow & 7) * 8;

    auto stage = [&](int buf, int kt) {
        bf16* ldsA = sh + buf*16384;
        bf16* ldsB = sh + buf*16384 + 8192;
#pragma unroll
        for (int s = 0; s < 4; ++s) {
            __builtin_amdgcn_global_load_lds(GPTR(Ag + (long)kt*64 + (long)s*32*K),
                                             LPTR(ldsA + s*2048 + tid*8), 16, 0, 0);
            __builtin_amdgcn_global_load_lds(GPTR(Bg + (long)kt*64 + (long)s*32*K),
                                             LPTR(ldsB + s*2048 + tid*8), 16, 0, 0);
        }
    };
    auto compute = [&](int buf) {
        const bf16* ldsA = sh + buf*16384;
        const bf16* ldsB = sh + buf*16384 + 8192;
#pragma unroll
        for (int kk = 0; kk < 2; ++kk) {
            bf16x8 af[4], bfr[4];
#pragma unroll
            for (int i = 0; i < 4; ++i)
                af[i] = *(const bf16x8*)&ldsA[(wr*64 + i*16 + arow)*64 + ((kk*32 + g8) ^ aswz)];
#pragma unroll
            for (int j = 0; j < 4; ++j)
                bfr[j] = *(const bf16x8*)&ldsB[(wc*64 + j*16 + arow)*64 + ((kk*32 + g8) ^ aswz)];
            __builtin_amdgcn_s_setprio(1);
#pragma unroll
            for (int i = 0; i < 4; ++i)
#pragma unroll
                for (int j = 0; j < 4; ++j)
                    acc[i][j] = __builtin_amdgcn_mfma_f32_16x16x32_bf16(af[i], bfr[j], acc[i][j], 0, 0, 0);
            __builtin_amdgcn_s_setprio(0);
        }
    };

    const int nkt = K / 64;
    stage(0, 0);
    for (int kt = 0; kt < nkt; ++kt) {
        if (kt + 1 < nkt) {
            stage((kt + 1) & 1, kt + 1);
            asm volatile("s_waitcnt vmcnt(8)" ::: "memory");
        } else {
            asm volatile("s_waitcnt vmcnt(0)" ::: "memory");
        }
        __builtin_amdgcn_s_barrier();
        __builtin_amdgcn_sched_barrier(0);
        compute(kt & 1);
        __builtin_amdgcn_sched_barrier(0);
        __builtin_amdgcn_s_barrier();
    }

#pragma unroll
    for (int j = 0; j < 4; ++j) {
        const int col = (int)bn*128 + wc*64 + j*16 + (lane & 15);
        const float bcol = bias[col];
#pragma unroll
        for (int i = 0; i < 4; ++i) {
            int row0 = (int)bm*128 + wr*64 + i*16 + ((lane>>4)<<2);
#pragma unroll
            for (int r = 0; r < 4; ++r)
                Out[(size_t)(row0 + r)*N + col] = acc[i][j][r] + bcol;
        }
    }
}

// ---------------- depthwise conv3d q-path (k=3, pad=1, stride (1,2,2)), bf16 out ----
__global__ __launch_bounds__(256) void dwconv_q(
    const bf16* __restrict__ in, const float* __restrict__ w,
    bf16* __restrict__ out, int total)
{
    __shared__ float lw[27*HD];
    for (int i = threadIdx.x; i < 27*HD; i += 256) {
        int c = i / 27, tap = i % 27;
        lw[tap*HD + c] = w[i];
    }
    __syncthreads();
    int idx = blockIdx.x*256 + threadIdx.x;
    if (idx >= total) return;
    int c8 = idx % 12;
    int p = idx / 12;
    int xo = p % WP_Q;
    int yo = (p / WP_Q) % HP_Q;
    int bh = p / (WP_Q*HP_Q);
    const bf16* ip = in + (size_t)bh * L0 * HD + c8*8;

    float acc[T0][8];
#pragma unroll
    for (int t = 0; t < T0; ++t)
#pragma unroll
        for (int j = 0; j < 8; ++j) acc[t][j] = 0.f;

#pragma unroll
    for (int dy = 0; dy < 3; ++dy) {
        int y = yo*2 + dy - 1;
        if ((unsigned)y >= (unsigned)H0) continue;
#pragma unroll
        for (int dx = 0; dx < 3; ++dx) {
            int x = xo*2 + dx - 1;
            if ((unsigned)x >= (unsigned)W0) continue;
            float wreg[3][8];
#pragma unroll
            for (int dt = 0; dt < 3; ++dt)
#pragma unroll
                for (int j = 0; j < 8; ++j)
                    wreg[dt][j] = lw[(dt*9 + dy*3 + dx)*HD + c8*8 + j];
            const bf16* colp = ip + ((size_t)(y*W0 + x))*HD;
#pragma unroll
            for (int t = 0; t < T0; ++t) {
                bf16x8 v = *(const bf16x8*)(colp + (size_t)t*H0*W0*HD);
                float f[8];
#pragma unroll
                for (int j = 0; j < 8; ++j) f[j] = (float)v[j];
#pragma unroll
                for (int dt = 0; dt < 3; ++dt) {
                    int to = t - dt + 1;
                    if (to < 0 || to >= T0) continue;
#pragma unroll
                    for (int j = 0; j < 8; ++j)
                        acc[to][j] += wreg[dt][j] * f[j];
                }
            }
        }
    }

#pragma unroll
    for (int to = 0; to < T0; ++to) {
        int l = (to*HP_Q + yo)*WP_Q + xo;
        bf16x8 ov;
#pragma unroll
        for (int j = 0; j < 8; ++j) ov[j] = (bf16)acc[to][j];
        *(bf16x8*)&out[((size_t)bh*LQ + l)*HD + c8*8] = ov;
    }
}

// ---------------- merged K+V conv from compact input, pad-zeroing folded in --------
__global__ __launch_bounds__(256) void dwconv_kv_all(
    const bf16* __restrict__ kv, const float* __restrict__ wk,
    const float* __restrict__ wv, bf16* __restrict__ kout, bf16* __restrict__ vtout)
{
    const int seg = blockIdx.x / 40;
    const int lb  = blockIdx.x % 40;
    const float* w = seg ? wv : wk;
    const bf16* in = kv + (size_t)seg * 16 * 3200 * HD;
    __shared__ float lw[27*HD];
    for (int i = threadIdx.x; i < 27*HD; i += 256) {
        int c = i / 27, tap = i % 27;
        lw[tap*HD + c] = w[i];
    }
    __syncthreads();

    if (lb >= 37) {   // pad-zero blocks
        int pid = (lb - 37)*256 + threadIdx.x;
        if (seg == 0) {
            for (int e = pid; e < 16*24*96; e += 768) {
                int bh = e / (24*96); int rem = e - bh*24*96;
                int l = LK + rem / 96; int c = rem % 96;
                kout[((size_t)bh*LKP + l)*HD + c] = (bf16)0.f;
            }
        } else {
            for (int e = pid; e < 16*96*24; e += 768) {
                int bh = e / (96*24); int rem = e - bh*96*24;
                int c = rem / 24; int l = LK + rem % 24;
                vtout[((size_t)bh*HD + c)*LKP + l] = (bf16)0.f;
            }
        }
        return;
    }

    int idx = lb*256 + threadIdx.x;
    if (idx >= 16*HP_K*WP_K*12) return;
    int c8 = idx % 12;
    int p = idx / 12;
    int xo = p % WP_K;
    int yo = (p / WP_K) % HP_K;
    int bh = p / (WP_K*HP_K);
    const bf16* ip = in + (size_t)bh * 3200 * HD + c8*8;

    float acc[T0][8];
#pragma unroll
    for (int t = 0; t < T0; ++t)
#pragma unroll
        for (int j = 0; j < 8; ++j) acc[t][j] = 0.f;

#pragma unroll
    for (int dy = 0; dy < 3; ++dy) {
        int yi = 3*yo + dy - 1;
        if ((unsigned)yi >= (unsigned)NYC) continue;
#pragma unroll
        for (int dx = 0; dx < 3; ++dx) {
            int xi = 3*xo + dx - 1;
            if ((unsigned)xi >= (unsigned)NYC) continue;
            float wreg[3][8];
#pragma unroll
            for (int dt = 0; dt < 3; ++dt)
#pragma unroll
                for (int j = 0; j < 8; ++j)
                    wreg[dt][j] = lw[(dt*9 + dy*3 + dx)*HD + c8*8 + j];
            const bf16* colp = ip + ((size_t)(yi*NYC + xi))*HD;
#pragma unroll
            for (int t = 0; t < T0; ++t) {
                bf16x8 v = *(const bf16x8*)(colp + (size_t)t*400*HD);
                float f[8];
#pragma unroll
                for (int j = 0; j < 8; ++j) f[j] = (float)v[j];
#pragma unroll
                for (int dt = 0; dt < 3; ++dt) {
                    int to = t - dt + 1;
                    if (to < 0 || to >= T0) continue;
#pragma unroll
                    for (int j = 0; j < 8; ++j)
                        acc[to][j] += wreg[dt][j] * f[j];
                }
            }
        }
    }

#pragma unroll
    for (int to = 0; to < T0; ++to) {
        int l = (to*HP_K + yo)*WP_K + xo;
        if (seg == 1) {
#pragma unroll
            for (int j = 0; j < 8; ++j)
                vtout[((size_t)bh*HD + c8*8 + j)*LKP + l] = (bf16)acc[to][j];
        } else {
            bf16x8 ov;
#pragma unroll
            for (int j = 0; j < 8; ++j) ov[j] = (bf16)acc[to][j];
            *(bf16x8*)&kout[((size_t)bh*LKP + l)*HD + c8*8] = ov;
        }
    }
}

// ---------------- MFMA attention: block = (b,h) x 64 q rows, wave = 16 q rows -------
__global__ __launch_bounds__(256) void attn_mfma(
    const bf16* __restrict__ q, const bf16* __restrict__ k,
    const bf16* __restrict__ vt, bf16* __restrict__ out)
{
    const int tid = threadIdx.x;
    const int lane = tid & 63;
    const int w = tid >> 6;
    const int col = lane & 15;
    const int g = lane >> 4;
    const int blk = blockIdx.x;
    const int qblk = blk % (LQ/64);
    const int bh = blk / (LQ/64);
    const int q0 = qblk*64 + w*16;

    const bf16* Qp  = q  + ((size_t)bh*LQ + q0)*HD;
    const bf16* Kp  = k  + (size_t)bh*LKP*HD;
    const bf16* VTp = vt + (size_t)bh*HD*LKP;

    bf16x8 qf[3];
#pragma unroll
    for (int c = 0; c < 3; ++c)
        qf[c] = *(const bf16x8*)&Qp[(size_t)col*HD + c*32 + g*8];

    f32x4 o[6];
#pragma unroll
    for (int t = 0; t < 6; ++t) o[t] = (f32x4){0.f,0.f,0.f,0.f};
    float lsum = 0.f;

    for (int kc = 0; kc < LKP/32; ++kc) {
        const int kvb = kc*32;
        uint32_t P[2][2];
#pragma unroll
        for (int s = 0; s < 2; ++s) {
            f32x4 acc = (f32x4){0.f,0.f,0.f,0.f};
#pragma unroll
            for (int c = 0; c < 3; ++c) {
                bf16x8 kf = *(const bf16x8*)&Kp[(size_t)(kvb + s*16 + col)*HD + c*32 + g*8];
                acc = __builtin_amdgcn_mfma_f32_16x16x32_bf16(kf, qf[c], acc, 0, 0, 0);
            }
            bf16x4 pb;
#pragma unroll
            for (int r = 0; r < 4; ++r) {
                int kv = kvb + s*16 + g*4 + r;
                float p = (kv < LK) ? __expf(acc[r]*SCALE) : 0.f;
                lsum += p;
                pb[r] = (bf16)p;
            }
            union { bf16x4 v; uint32_t u[2]; } pk; pk.v = pb;
            P[s][0] = pk.u[0]; P[s][1] = pk.u[1];
        }
        uint32_t sa0 = (g < 2) ? P[1][0] : P[0][0];
        uint32_t sa1 = (g < 2) ? P[1][1] : P[0][1];
        uint32_t tb0 = (g < 2) ? P[0][0] : P[1][0];
        uint32_t tb1 = (g < 2) ? P[0][1] : P[1][1];
        uint32_t R32_0 = (uint32_t)__shfl_xor((int)sa0, 32);
        uint32_t R32_1 = (uint32_t)__shfl_xor((int)sa1, 32);
        uint32_t R48_0 = (uint32_t)__shfl_xor((int)sa0, 48);
        uint32_t R48_1 = (uint32_t)__shfl_xor((int)sa1, 48);
        uint32_t R16_0 = (uint32_t)__shfl_xor((int)tb0, 16);
        uint32_t R16_1 = (uint32_t)__shfl_xor((int)tb1, 16);
        union { uint32_t u[4]; bf16x8 v; } pf;
        pf.u[0] = (g == 0) ? P[0][0] : (g == 1) ? R48_0 : (g == 2) ? R32_0 : R16_0;
        pf.u[1] = (g == 0) ? P[0][1] : (g == 1) ? R48_1 : (g == 2) ? R32_1 : R16_1;
        pf.u[2] = (g == 0) ? R16_0 : (g == 1) ? R32_0 : (g == 2) ? R48_0 : P[1][0];
        pf.u[3] = (g == 0) ? R16_1 : (g == 1) ? R32_1 : (g == 2) ? R48_1 : P[1][1];
#pragma unroll
        for (int t = 0; t < 6; ++t) {
            bf16x8 vf = *(const bf16x8*)&VTp[(size_t)(t*16 + col)*LKP + kvb + g*8];
            o[t] = __builtin_amdgcn_mfma_f32_16x16x32_bf16(vf, pf.v, o[t], 0, 0, 0);
        }
    }

    lsum += __shfl_xor(lsum, 16);
    lsum += __shfl_xor(lsum, 32);
    float inv = 1.f / lsum;

    const int b = bh >> 3, nh = bh & 7;
    size_t obase = ((size_t)b*LQ + q0 + col)*CDIM + (size_t)nh*HD;
#pragma unroll
    for (int t = 0; t < 6; ++t) {
        bf16x4 qres = *(const bf16x4*)&Qp[(size_t)col*HD + t*16 + g*4];
        bf16x4 ov;
#pragma unroll
        for (int r = 0; r < 4; ++r)
            ov[r] = (bf16)(o[t][r]*inv + (float)qres[r]);
        *(bf16x4*)&out[obase + t*16 + g*4] = ov;
    }
}

extern "C" void kernel_launch(void* const* d_in, const int* in_sizes, int n_in,
                              void* d_out, int out_size, void* d_ws, size_t ws_size,
                              hipStream_t stream) {
    const float* x      = (const float*)d_in[0];
    const float* qkv_w  = (const float*)d_in[1];
    const float* qkv_b  = (const float*)d_in[2];
    const float* proj_w = (const float*)d_in[3];
    const float* proj_b = (const float*)d_in[4];
    const float* pq_w   = (const float*)d_in[5];
    const float* pk_w   = (const float*)d_in[6];
    const float* pv_w   = (const float*)d_in[7];

    uint8_t* ws = (uint8_t*)d_ws;
    bf16* qg_out   = (bf16*)(ws);                  // 77,070,336 B  [16][L0][96] (GELU'd Q)
    bf16* kv_c     = (bf16*)(ws +  77070336);      // 19,660,800 B  [2][16][3200][96]
    bf16* wqkv_bf  = (bf16*)(ws +  96731136);      // 3,538,944 B
    bf16* wproj_bf = (bf16*)(ws + 100270080);      // 1,179,648 B
    bf16* q_bf     = (bf16*)(ws + 101449728);      // 19,267,584 B  [16][6272][96]
    bf16* k_bf     = (bf16*)(ws + 120717312);      // 1,277,952 B   [16][416][96]
    bf16* vt_bf    = (bf16*)(ws + 121995264);      // 1,277,952 B   [16][96][416]
    bf16* attn_o   = (bf16*)(ws + 123273216);      // 19,267,584 B -> end 142,540,800

    cvt_w<<<576, 256, 0, stream>>>((const f4*)qkv_w, (const f4*)proj_w,
                                   (bf16x4*)wqkv_bf, (bf16x4*)wproj_bf);

    // Q-part GEMM: fp32 A direct. M=50176 (392 bm), N=768 (6 bn).
    gemm_f32a<0><<<392*6, 256, 0, stream>>>(
        x, wqkv_bf, qkv_b, qg_out, 50176, 768, 768, 6);

    // K/V compact GEMM: fp32 A gathered. M=6400 (50 bm), N=1536 (12 bn).
    gemm_f32a<2><<<50*12, 256, 0, stream>>>(
        x, wqkv_bf + (size_t)768*768, qkv_b + 768, kv_c, MKV, 1536, 768, 12);

    dwconv_q<<<588, 256, 0, stream>>>(qg_out, pq_w, q_bf, 16*HP_Q*WP_Q*12);
    dwconv_kv_all<<<80, 256, 0, stream>>>(kv_c, pk_w, pv_w, k_bf, vt_bf);

    attn_mfma<<<16*(LQ/64), 256, 0, stream>>>(q_bf, k_bf, vt_bf, attn_o);

    gemm_proj<<<6*98, 256, 0, stream>>>(
        attn_o, wproj_bf, proj_b, (float*)d_out, 12544, 768, 768, 6);
}

// Round 11
// 301.245 us; speedup vs baseline: 1.6813x; 1.0444x over previous
//
#include <hip/hip_runtime.h>
#include <cstdint>

#define NH 8
#define HD 96
#define CDIM 768
#define BQ 2
#define T0 8
#define H0 56
#define W0 56
#define L0 (T0*H0*W0)     // 25088
#define HP_Q 28
#define WP_Q 28
#define LQ (T0*HP_Q*WP_Q) // 6272
#define HP_K 7
#define WP_K 7
#define LK (T0*HP_K*WP_K) // 392
#define LKP 416           // kv padded to multiple of 32
#define SCALE 0.10206207261596577f
#define NYC 20
#define MKV 6400          // 2*8*400 gathered kv rows (50 x 128)
#define NBQ 2352          // Q-gemm blocks: 392 bm x 6 bn
#define NBKV 600          // KV-gemm blocks: 50 bm x 12 bn

typedef __bf16 bf16;
typedef bf16 bf16x4 __attribute__((ext_vector_type(4)));
typedef bf16 bf16x8 __attribute__((ext_vector_type(8)));
typedef float f32x4 __attribute__((ext_vector_type(4)));
typedef float f4 __attribute__((ext_vector_type(4)));

#define GPTR(x) ((const __attribute__((address_space(1))) void*)(x))
#define LPTR(x) ((__attribute__((address_space(3))) void*)(x))

// fast erf-GELU: A&S 7.1.27 rational erf approx, |err(erf)| <= 5e-4 (<< bf16 rounding)
__device__ __forceinline__ float fast_gelu(float x) {
    float z = __builtin_fabsf(x) * 0.7071067811865476f;
    float p = 1.f + z*(0.278393f + z*(0.230389f + z*(0.000972f + z*0.078108f)));
    p = p * p;
    p = p * p;
    float e = 1.f - __builtin_amdgcn_rcpf(p);   // erf(|x|/sqrt2)
    float erfv = (x < 0.f) ? -e : e;
    return 0.5f * x * (1.f + erfv);
}

// ---------------- weight fp32 -> bf16 (x stays fp32; GEMMs consume it directly) ----
#define NW4 442368
#define NP4 147456
__global__ void cvt_w(const f4* __restrict__ wq, const f4* __restrict__ wp,
                      bf16x4* __restrict__ wqo, bf16x4* __restrict__ wpo) {
    const long total = NW4 + NP4;
    long stride = (long)gridDim.x * blockDim.x;
    for (long i = (long)blockIdx.x * blockDim.x + threadIdx.x; i < total; i += stride) {
        f4 v; bf16x4* o;
        if (i < NW4) { v = wq[i]; o = wqo + i; }
        else         { v = wp[i - NW4]; o = wpo + (i - NW4); }
        bf16x4 t;
        t[0] = (bf16)v[0]; t[1] = (bf16)v[1]; t[2] = (bf16)v[2]; t[3] = (bf16)v[3];
        *o = t;
    }
}

// map compact grid index (0..19) -> original spatial coord (y or x)
__device__ __forceinline__ int cmap(int i) {
    return ((i + 1) / 3) * 8 + (i + 1) % 3 - 1;
}

// ======== merged Q + KV 128x128 GEMM, fp32 A staged direct (one dispatch) ==========
// blocks [0, NBQ):       Q-part.  M=50176, N=768 (6 bn), GELU, scatter [16][L0][96]
// blocks [NBQ, NBQ+NBKV): KV.     M=6400 gathered rows, N=1536 (12 bn), GELU,
//                                 compact store [part][b*8+nh][t*400+rr][96]
// BK=32 dbuf (48KB -> 3 blocks/CU); single barrier per K-iter (see R11 derivation);
// counted vmcnt(6); A cvt fp32->bf16 at ds_read; T2 swizzles both operands.
__global__ __launch_bounds__(256) void gemm_qkv(
    const float* __restrict__ A, const bf16* __restrict__ Wq,
    const float* __restrict__ bias_q, bf16* __restrict__ OutQ,
    bf16* __restrict__ OutKV)
{
    __shared__ uint8_t sh[2*24576];
    const int tid = threadIdx.x;
    const int lane = tid & 63;
    const int w = tid >> 6;
    const int wr = w >> 1, wc = w & 1;
    const int g = lane >> 4;
    const int ar = lane & 15;
    const int K = 768;

    // T1: XCD-chunked bijective swizzle over the full merged grid (2952 = 8*369)
    const int nwg = gridDim.x;
    const int q_ = nwg >> 3, r_ = nwg & 7;
    const int xcd = blockIdx.x & 7, off = blockIdx.x >> 3;
    const int swz = (xcd < r_ ? xcd*(q_+1) : r_*(q_+1) + (xcd - r_)*q_) + off;

    const bool isQ = swz < NBQ;
    const int idx = isQ ? swz : swz - NBQ;
    const int NBN = isQ ? 6 : 12;
    const long bm = idx / NBN, bn = idx % NBN;
    const bf16* B = isQ ? Wq : Wq + (size_t)768*768;
    const float* bias = isQ ? bias_q : bias_q + 768;

    f32x4 acc[4][4];
#pragma unroll
    for (int i = 0; i < 4; ++i)
#pragma unroll
        for (int j = 0; j < 4; ++j) acc[i][j] = (f32x4){0.f,0.f,0.f,0.f};

    // A staging: 4 rounds x 32 rows; thread covers (row = s*32 + t>>3, lds slot t&7)
    const int arow_s = tid >> 3;                     // 0..31
    const int csa = (tid & 7) ^ (arow_s & 7);        // inverse swizzle on SOURCE
    long aoff[4];
#pragma unroll
    for (int s = 0; s < 4; ++s) {
        int rA = (int)bm*128 + s*32 + arow_s;
        if (!isQ) {
            int b = rA / 3200; int r = rA - b*3200;
            int t = r / 400;  int rr = r - t*400;
            int yi = rr / NYC, xi = rr - yi*NYC;
            aoff[s] = ((long)b*L0 + (t*H0 + cmap(yi))*W0 + cmap(xi)) * (long)K;
        } else {
            aoff[s] = (long)rA * K;
        }
    }
    // B staging: 2 rounds x 64 rows; thread covers (row = t>>2, lds slot t&3)
    const int brow_s = tid >> 2;                     // 0..63
    const int csb = (tid & 3) ^ ((tid >> 3) & 3);    // = slot ^ ((row>>1)&3)
    const bf16* Bg = B + (bn*128 + brow_s)*(long)K + csb*8;

    auto stage = [&](int buf, int kt) {
        uint8_t* base = sh + buf*24576;
#pragma unroll
        for (int s = 0; s < 4; ++s)
            __builtin_amdgcn_global_load_lds(GPTR(A + aoff[s] + kt*32 + csa*4),
                LPTR(base + s*4096 + tid*16), 16, 0, 0);
#pragma unroll
        for (int s = 0; s < 2; ++s)
            __builtin_amdgcn_global_load_lds(GPTR(Bg + (long)kt*32 + (long)s*64*K),
                LPTR(base + 16384 + s*4096 + tid*16), 16, 0, 0);
    };
    auto compute = [&](int buf) {
        const float* ldsA = (const float*)(sh + buf*24576);
        const bf16* ldsB = (const bf16*)(sh + buf*24576 + 16384);
        bf16x8 af[4], bfr[4];
#pragma unroll
        for (int i = 0; i < 4; ++i) {
            int R = wr*64 + i*16 + ar;
            f32x4 lo = *(const f32x4*)&ldsA[R*32 + (((2*g    ) ^ (R & 7))*4)];
            f32x4 hi = *(const f32x4*)&ldsA[R*32 + (((2*g + 1) ^ (R & 7))*4)];
            bf16x8 t;
            t[0] = (bf16)lo[0]; t[1] = (bf16)lo[1]; t[2] = (bf16)lo[2]; t[3] = (bf16)lo[3];
            t[4] = (bf16)hi[0]; t[5] = (bf16)hi[1]; t[6] = (bf16)hi[2]; t[7] = (bf16)hi[3];
            af[i] = t;
        }
#pragma unroll
        for (int j = 0; j < 4; ++j) {
            int R = wc*64 + j*16 + ar;
            bfr[j] = *(const bf16x8*)&ldsB[R*32 + ((g ^ ((R >> 1) & 3))*8)];
        }
        __builtin_amdgcn_s_setprio(1);
#pragma unroll
        for (int i = 0; i < 4; ++i)
#pragma unroll
            for (int j = 0; j < 4; ++j)
                acc[i][j] = __builtin_amdgcn_mfma_f32_16x16x32_bf16(af[i], bfr[j], acc[i][j], 0, 0, 0);
        __builtin_amdgcn_s_setprio(0);
    };

    const int nkt = K / 32;   // 24
    stage(0, 0);
    // single-barrier pipeline: vmcnt(6) drains this thread's tile-kt loads (6 newest
    // outstanding are kt+1's once issued; here wait BEFORE issuing next stage), then
    // barrier syncs all threads' drains; stage(kt+1) into buf nxt is safe because
    // every thread's reads of nxt (tile kt-1's compute) completed before its barrier.
    for (int kt = 0; kt < nkt; ++kt) {
        const int cur = kt & 1;
        asm volatile("s_waitcnt vmcnt(0)" ::: "memory");   // only tile-kt loads pending
        __builtin_amdgcn_s_barrier();
        __builtin_amdgcn_sched_barrier(0);
        if (kt + 1 < nkt) stage(cur ^ 1, kt + 1);
        compute(cur);
        __builtin_amdgcn_sched_barrier(0);
    }

    // ---------------- epilogue: LDS transpose + GELU + coalesced bf16x8 stores ------
    __syncthreads();                       // tls reuses sh; other waves may still read
    bf16* tls = (bf16*)sh;                 // 128 x 136 bf16 = 34.8 KB
#pragma unroll
    for (int j = 0; j < 4; ++j) {
        const int colb = (int)bn*128 + wc*64 + j*16;
        const int lcol = wc*64 + j*16 + ar;
        const float bcol = bias[colb + ar];
#pragma unroll
        for (int i = 0; i < 4; ++i) {
            int lrow0 = wr*64 + i*16 + (g << 2);
#pragma unroll
            for (int r = 0; r < 4; ++r)
                tls[(lrow0 + r)*136 + lcol] = (bf16)fast_gelu(acc[i][j][r] + bcol);
        }
    }
    __syncthreads();
#pragma unroll
    for (int it = 0; it < 8; ++it) {
        int idx2 = it*256 + tid;
        int mloc = idx2 >> 4;
        int ck = idx2 & 15;
        bf16x8 v = *(const bf16x8*)&tls[mloc*136 + ck*8];
        int m = (int)bm*128 + mloc;
        int col = (int)bn*128 + ck*8;
        if (isQ) {
            int nh = col / HD;
            int c = col - nh*HD;
            int bflag = m >= L0;              // M = 2*L0
            int l = m - (bflag ? L0 : 0);
            size_t addr = ((size_t)(bflag*8 + nh)*L0 + l)*HD + c;
            *(bf16x8*)&OutQ[addr] = v;
        } else {
            int part = col / 768;
            int cb = col - part*768;
            int nh = cb / HD;
            int c = cb - nh*HD;
            int b = m / 3200; int r = m - b*3200;   // r = t*400 + rr
            size_t addr = ((size_t)(part*16 + b*8 + nh)*3200 + r)*HD + c;
            *(bf16x8*)&OutKV[addr] = v;
        }
    }
}

// ---------------- 128x128 bf16-A GEMM — proj only (single-barrier pipeline) --------
__global__ __launch_bounds__(256) void gemm_proj(
    const bf16* __restrict__ A, const bf16* __restrict__ B,
    const float* __restrict__ bias, float* __restrict__ Out,
    int M, int N, int K, int NBN)
{
    __shared__ bf16 sh[2*16384];
    const int tid = threadIdx.x;
    const int lane = tid & 63;
    const int w = tid >> 6;
    const int wr = w >> 1, wc = w & 1;

    const int nwg = gridDim.x;
    const int q_ = nwg >> 3, r_ = nwg & 7;
    const int xcd = blockIdx.x & 7, off = blockIdx.x >> 3;
    const int swz = (xcd < r_ ? xcd*(q_+1) : r_*(q_+1) + (xcd - r_)*q_) + off;
    const long bn = swz % NBN, bm = swz / NBN;

    f32x4 acc[4][4];
#pragma unroll
    for (int i = 0; i < 4; ++i)
#pragma unroll
        for (int j = 0; j < 4; ++j) acc[i][j] = (f32x4){0.f,0.f,0.f,0.f};

    const int trow = tid >> 3;
    const int tchunk = (tid & 7) ^ (trow & 7);
    const bf16* Ag = A + (bm*128 + trow)*(long)K + tchunk*8;
    const bf16* Bg = B + (bn*128 + trow)*(long)K + tchunk*8;

    const int arow = lane & 15;
    const int g8 = (lane >> 4) * 8;
    const int aswz = (arow & 7) * 8;

    auto stage = [&](int buf, int kt) {
        bf16* ldsA = sh + buf*16384;
        bf16* ldsB = sh + buf*16384 + 8192;
#pragma unroll
        for (int s = 0; s < 4; ++s) {
            __builtin_amdgcn_global_load_lds(GPTR(Ag + (long)kt*64 + (long)s*32*K),
                                             LPTR(ldsA + s*2048 + tid*8), 16, 0, 0);
            __builtin_amdgcn_global_load_lds(GPTR(Bg + (long)kt*64 + (long)s*32*K),
                                             LPTR(ldsB + s*2048 + tid*8), 16, 0, 0);
        }
    };
    auto compute = [&](int buf) {
        const bf16* ldsA = sh + buf*16384;
        const bf16* ldsB = sh + buf*16384 + 8192;
#pragma unroll
        for (int kk = 0; kk < 2; ++kk) {
            bf16x8 af[4], bfr[4];
#pragma unroll
            for (int i = 0; i < 4; ++i)
                af[i] = *(const bf16x8*)&ldsA[(wr*64 + i*16 + arow)*64 + ((kk*32 + g8) ^ aswz)];
#pragma unroll
            for (int j = 0; j < 4; ++j)
                bfr[j] = *(const bf16x8*)&ldsB[(wc*64 + j*16 + arow)*64 + ((kk*32 + g8) ^ aswz)];
            __builtin_amdgcn_s_setprio(1);
#pragma unroll
            for (int i = 0; i < 4; ++i)
#pragma unroll
                for (int j = 0; j < 4; ++j)
                    acc[i][j] = __builtin_amdgcn_mfma_f32_16x16x32_bf16(af[i], bfr[j], acc[i][j], 0, 0, 0);
            __builtin_amdgcn_s_setprio(0);
        }
    };

    const int nkt = K / 64;
    stage(0, 0);
    for (int kt = 0; kt < nkt; ++kt) {
        const int cur = kt & 1;
        asm volatile("s_waitcnt vmcnt(0)" ::: "memory");
        __builtin_amdgcn_s_barrier();
        __builtin_amdgcn_sched_barrier(0);
        if (kt + 1 < nkt) stage(cur ^ 1, kt + 1);
        compute(cur);
        __builtin_amdgcn_sched_barrier(0);
    }

#pragma unroll
    for (int j = 0; j < 4; ++j) {
        const int col = (int)bn*128 + wc*64 + j*16 + (lane & 15);
        const float bcol = bias[col];
#pragma unroll
        for (int i = 0; i < 4; ++i) {
            int row0 = (int)bm*128 + wr*64 + i*16 + ((lane>>4)<<2);
#pragma unroll
            for (int r = 0; r < 4; ++r)
                Out[(size_t)(row0 + r)*N + col] = acc[i][j][r] + bcol;
        }
    }
}

// ---------------- merged depthwise conv3d: q-path + kv-path in one dispatch --------
// blocks [0,588): q (stride 1,2,2) from [16][L0][96] -> [16][LQ][96]
// blocks [588,668): k/v from compact [2][16][3200][96]; k -> [16][LKP][96],
//                   v -> [16][96][LKP] transposed; pad regions zeroed.
__global__ __launch_bounds__(256) void dwconv_all(
    const bf16* __restrict__ qin, const bf16* __restrict__ kv,
    const float* __restrict__ wq, const float* __restrict__ wk,
    const float* __restrict__ wv, bf16* __restrict__ qout,
    bf16* __restrict__ kout, bf16* __restrict__ vtout)
{
    __shared__ float lw[27*HD];
    const int blk = blockIdx.x;
    if (blk < 588) {
        // ---------------- q path ----------------
        for (int i = threadIdx.x; i < 27*HD; i += 256) {
            int c = i / 27, tap = i % 27;
            lw[tap*HD + c] = wq[i];
        }
        __syncthreads();
        int idx = blk*256 + threadIdx.x;
        if (idx >= 16*HP_Q*WP_Q*12) return;
        int c8 = idx % 12;
        int p = idx / 12;
        int xo = p % WP_Q;
        int yo = (p / WP_Q) % HP_Q;
        int bh = p / (WP_Q*HP_Q);
        const bf16* ip = qin + (size_t)bh * L0 * HD + c8*8;

        float acc[T0][8];
#pragma unroll
        for (int t = 0; t < T0; ++t)
#pragma unroll
            for (int j = 0; j < 8; ++j) acc[t][j] = 0.f;

#pragma unroll
        for (int dy = 0; dy < 3; ++dy) {
            int y = yo*2 + dy - 1;
            if ((unsigned)y >= (unsigned)H0) continue;
#pragma unroll
            for (int dx = 0; dx < 3; ++dx) {
                int x = xo*2 + dx - 1;
                if ((unsigned)x >= (unsigned)W0) continue;
                float wreg[3][8];
#pragma unroll
                for (int dt = 0; dt < 3; ++dt)
#pragma unroll
                    for (int j = 0; j < 8; ++j)
                        wreg[dt][j] = lw[(dt*9 + dy*3 + dx)*HD + c8*8 + j];
                const bf16* colp = ip + ((size_t)(y*W0 + x))*HD;
#pragma unroll
                for (int t = 0; t < T0; ++t) {
                    bf16x8 v = *(const bf16x8*)(colp + (size_t)t*H0*W0*HD);
                    float f[8];
#pragma unroll
                    for (int j = 0; j < 8; ++j) f[j] = (float)v[j];
#pragma unroll
                    for (int dt = 0; dt < 3; ++dt) {
                        int to = t - dt + 1;
                        if (to < 0 || to >= T0) continue;
#pragma unroll
                        for (int j = 0; j < 8; ++j)
                            acc[to][j] += wreg[dt][j] * f[j];
                    }
                }
            }
        }

#pragma unroll
        for (int to = 0; to < T0; ++to) {
            int l = (to*HP_Q + yo)*WP_Q + xo;
            bf16x8 ov;
#pragma unroll
            for (int j = 0; j < 8; ++j) ov[j] = (bf16)acc[to][j];
            *(bf16x8*)&qout[((size_t)bh*LQ + l)*HD + c8*8] = ov;
        }
        return;
    }

    // ---------------- kv path ----------------
    const int kb = blk - 588;          // 0..79
    const int seg = kb / 40;
    const int lb  = kb % 40;
    const float* w = seg ? wv : wk;
    const bf16* in = kv + (size_t)seg * 16 * 3200 * HD;
    for (int i = threadIdx.x; i < 27*HD; i += 256) {
        int c = i / 27, tap = i % 27;
        lw[tap*HD + c] = w[i];
    }
    __syncthreads();

    if (lb >= 37) {   // pad-zero blocks
        int pid = (lb - 37)*256 + threadIdx.x;
        if (seg == 0) {
            for (int e = pid; e < 16*24*96; e += 768) {
                int bh = e / (24*96); int rem = e - bh*24*96;
                int l = LK + rem / 96; int c = rem % 96;
                kout[((size_t)bh*LKP + l)*HD + c] = (bf16)0.f;
            }
        } else {
            for (int e = pid; e < 16*96*24; e += 768) {
                int bh = e / (96*24); int rem = e - bh*96*24;
                int c = rem / 24; int l = LK + rem % 24;
                vtout[((size_t)bh*HD + c)*LKP + l] = (bf16)0.f;
            }
        }
        return;
    }

    int idx = lb*256 + threadIdx.x;
    if (idx >= 16*HP_K*WP_K*12) return;
    int c8 = idx % 12;
    int p = idx / 12;
    int xo = p % WP_K;
    int yo = (p / WP_K) % HP_K;
    int bh = p / (WP_K*HP_K);
    const bf16* ip = in + (size_t)bh * 3200 * HD + c8*8;

    float acc[T0][8];
#pragma unroll
    for (int t = 0; t < T0; ++t)
#pragma unroll
        for (int j = 0; j < 8; ++j) acc[t][j] = 0.f;

#pragma unroll
    for (int dy = 0; dy < 3; ++dy) {
        int yi = 3*yo + dy - 1;
        if ((unsigned)yi >= (unsigned)NYC) continue;
#pragma unroll
        for (int dx = 0; dx < 3; ++dx) {
            int xi = 3*xo + dx - 1;
            if ((unsigned)xi >= (unsigned)NYC) continue;
            float wreg[3][8];
#pragma unroll
            for (int dt = 0; dt < 3; ++dt)
#pragma unroll
                for (int j = 0; j < 8; ++j)
                    wreg[dt][j] = lw[(dt*9 + dy*3 + dx)*HD + c8*8 + j];
            const bf16* colp = ip + ((size_t)(yi*NYC + xi))*HD;
#pragma unroll
            for (int t = 0; t < T0; ++t) {
                bf16x8 v = *(const bf16x8*)(colp + (size_t)t*400*HD);
                float f[8];
#pragma unroll
                for (int j = 0; j < 8; ++j) f[j] = (float)v[j];
#pragma unroll
                for (int dt = 0; dt < 3; ++dt) {
                    int to = t - dt + 1;
                    if (to < 0 || to >= T0) continue;
#pragma unroll
                    for (int j = 0; j < 8; ++j)
                        acc[to][j] += wreg[dt][j] * f[j];
                }
            }
        }
    }

#pragma unroll
    for (int to = 0; to < T0; ++to) {
        int l = (to*HP_K + yo)*WP_K + xo;
        if (seg == 1) {
#pragma unroll
            for (int j = 0; j < 8; ++j)
                vtout[((size_t)bh*HD + c8*8 + j)*LKP + l] = (bf16)acc[to][j];
        } else {
            bf16x8 ov;
#pragma unroll
            for (int j = 0; j < 8; ++j) ov[j] = (bf16)acc[to][j];
            *(bf16x8*)&kout[((size_t)bh*LKP + l)*HD + c8*8] = ov;
        }
    }
}

// ---------------- MFMA attention: block = (b,h) x 64 q rows, wave = 16 q rows -------
__global__ __launch_bounds__(256) void attn_mfma(
    const bf16* __restrict__ q, const bf16* __restrict__ k,
    const bf16* __restrict__ vt, bf16* __restrict__ out)
{
    const int tid = threadIdx.x;
    const int lane = tid & 63;
    const int w = tid >> 6;
    const int col = lane & 15;
    const int g = lane >> 4;
    const int blk = blockIdx.x;
    const int qblk = blk % (LQ/64);
    const int bh = blk / (LQ/64);
    const int q0 = qblk*64 + w*16;

    const bf16* Qp  = q  + ((size_t)bh*LQ + q0)*HD;
    const bf16* Kp  = k  + (size_t)bh*LKP*HD;
    const bf16* VTp = vt + (size_t)bh*HD*LKP;

    bf16x8 qf[3];
#pragma unroll
    for (int c = 0; c < 3; ++c)
        qf[c] = *(const bf16x8*)&Qp[(size_t)col*HD + c*32 + g*8];

    f32x4 o[6];
#pragma unroll
    for (int t = 0; t < 6; ++t) o[t] = (f32x4){0.f,0.f,0.f,0.f};
    float lsum = 0.f;

    for (int kc = 0; kc < LKP/32; ++kc) {
        const int kvb = kc*32;
        uint32_t P[2][2];
#pragma unroll
        for (int s = 0; s < 2; ++s) {
            f32x4 acc = (f32x4){0.f,0.f,0.f,0.f};
#pragma unroll
            for (int c = 0; c < 3; ++c) {
                bf16x8 kf = *(const bf16x8*)&Kp[(size_t)(kvb + s*16 + col)*HD + c*32 + g*8];
                acc = __builtin_amdgcn_mfma_f32_16x16x32_bf16(kf, qf[c], acc, 0, 0, 0);
            }
            bf16x4 pb;
#pragma unroll
            for (int r = 0; r < 4; ++r) {
                int kv = kvb + s*16 + g*4 + r;
                float p = (kv < LK) ? __expf(acc[r]*SCALE) : 0.f;
                lsum += p;
                pb[r] = (bf16)p;
            }
            union { bf16x4 v; uint32_t u[2]; } pk; pk.v = pb;
            P[s][0] = pk.u[0]; P[s][1] = pk.u[1];
        }
        uint32_t sa0 = (g < 2) ? P[1][0] : P[0][0];
        uint32_t sa1 = (g < 2) ? P[1][1] : P[0][1];
        uint32_t tb0 = (g < 2) ? P[0][0] : P[1][0];
        uint32_t tb1 = (g < 2) ? P[0][1] : P[1][1];
        uint32_t R32_0 = (uint32_t)__shfl_xor((int)sa0, 32);
        uint32_t R32_1 = (uint32_t)__shfl_xor((int)sa1, 32);
        uint32_t R48_0 = (uint32_t)__shfl_xor((int)sa0, 48);
        uint32_t R48_1 = (uint32_t)__shfl_xor((int)sa1, 48);
        uint32_t R16_0 = (uint32_t)__shfl_xor((int)tb0, 16);
        uint32_t R16_1 = (uint32_t)__shfl_xor((int)tb1, 16);
        union { uint32_t u[4]; bf16x8 v; } pf;
        pf.u[0] = (g == 0) ? P[0][0] : (g == 1) ? R48_0 : (g == 2) ? R32_0 : R16_0;
        pf.u[1] = (g == 0) ? P[0][1] : (g == 1) ? R48_1 : (g == 2) ? R32_1 : R16_1;
        pf.u[2] = (g == 0) ? R16_0 : (g == 1) ? R32_0 : (g == 2) ? R48_0 : P[1][0];
        pf.u[3] = (g == 0) ? R16_1 : (g == 1) ? R32_1 : (g == 2) ? R48_1 : P[1][1];
#pragma unroll
        for (int t = 0; t < 6; ++t) {
            bf16x8 vf = *(const bf16x8*)&VTp[(size_t)(t*16 + col)*LKP + kvb + g*8];
            o[t] = __builtin_amdgcn_mfma_f32_16x16x32_bf16(vf, pf.v, o[t], 0, 0, 0);
        }
    }

    lsum += __shfl_xor(lsum, 16);
    lsum += __shfl_xor(lsum, 32);
    float inv = 1.f / lsum;

    const int b = bh >> 3, nh = bh & 7;
    size_t obase = ((size_t)b*LQ + q0 + col)*CDIM + (size_t)nh*HD;
#pragma unroll
    for (int t = 0; t < 6; ++t) {
        bf16x4 qres = *(const bf16x4*)&Qp[(size_t)col*HD + t*16 + g*4];
        bf16x4 ov;
#pragma unroll
        for (int r = 0; r < 4; ++r)
            ov[r] = (bf16)(o[t][r]*inv + (float)qres[r]);
        *(bf16x4*)&out[obase + t*16 + g*4] = ov;
    }
}

extern "C" void kernel_launch(void* const* d_in, const int* in_sizes, int n_in,
                              void* d_out, int out_size, void* d_ws, size_t ws_size,
                              hipStream_t stream) {
    const float* x      = (const float*)d_in[0];
    const float* qkv_w  = (const float*)d_in[1];
    const float* qkv_b  = (const float*)d_in[2];
    const float* proj_w = (const float*)d_in[3];
    const float* proj_b = (const float*)d_in[4];
    const float* pq_w   = (const float*)d_in[5];
    const float* pk_w   = (const float*)d_in[6];
    const float* pv_w   = (const float*)d_in[7];

    uint8_t* ws = (uint8_t*)d_ws;
    bf16* qg_out   = (bf16*)(ws);                  // 77,070,336 B  [16][L0][96] (GELU'd Q)
    bf16* kv_c     = (bf16*)(ws +  77070336);      // 19,660,800 B  [2][16][3200][96]
    bf16* wqkv_bf  = (bf16*)(ws +  96731136);      // 3,538,944 B
    bf16* wproj_bf = (bf16*)(ws + 100270080);      // 1,179,648 B
    bf16* q_bf     = (bf16*)(ws + 101449728);      // 19,267,584 B  [16][6272][96]
    bf16* k_bf     = (bf16*)(ws + 120717312);      // 1,277,952 B   [16][416][96]
    bf16* vt_bf    = (bf16*)(ws + 121995264);      // 1,277,952 B   [16][96][416]
    bf16* attn_o   = (bf16*)(ws + 123273216);      // 19,267,584 B -> end 142,540,800

    cvt_w<<<576, 256, 0, stream>>>((const f4*)qkv_w, (const f4*)proj_w,
                                   (bf16x4*)wqkv_bf, (bf16x4*)wproj_bf);

    // merged Q + KV GEMM (2952 blocks, one dispatch)
    gemm_qkv<<<NBQ + NBKV, 256, 0, stream>>>(x, wqkv_bf, qkv_b, qg_out, kv_c);

    // merged convs (q + k + v + pad-zeroing, one dispatch)
    dwconv_all<<<668, 256, 0, stream>>>(qg_out, kv_c, pq_w, pk_w, pv_w,
                                        q_bf, k_bf, vt_bf);

    attn_mfma<<<16*(LQ/64), 256, 0, stream>>>(q_bf, k_bf, vt_bf, attn_o);

    gemm_proj<<<6*98, 256, 0, stream>>>(
        attn_o, wproj_bf, proj_b, (float*)d_out, 12544, 768, 768, 6);
}

// Round 12
// 294.229 us; speedup vs baseline: 1.7214x; 1.0238x over previous
//
#include <hip/hip_runtime.h>
#include <cstdint>

#define NH 8
#define HD 96
#define CDIM 768
#define BQ 2
#define T0 8
#define H0 56
#define W0 56
#define L0 (T0*H0*W0)     // 25088
#define HP_Q 28
#define WP_Q 28
#define LQ (T0*HP_Q*WP_Q) // 6272
#define HP_K 7
#define WP_K 7
#define LK (T0*HP_K*WP_K) // 392
#define LKP 416           // kv padded to multiple of 32
#define SCALE 0.10206207261596577f
#define NYC 20
#define MKV 6400          // 2*8*400 gathered kv rows (50 x 128)
#define NBQ 2352          // Q-gemm blocks: 392 bm x 6 bn
#define NBKV 600          // KV-gemm blocks: 50 bm x 12 bn

typedef __bf16 bf16;
typedef bf16 bf16x4 __attribute__((ext_vector_type(4)));
typedef bf16 bf16x8 __attribute__((ext_vector_type(8)));
typedef float f32x4 __attribute__((ext_vector_type(4)));
typedef float f4 __attribute__((ext_vector_type(4)));

#define GPTR(x) ((const __attribute__((address_space(1))) void*)(x))
#define LPTR(x) ((__attribute__((address_space(3))) void*)(x))

// fast erf-GELU: A&S 7.1.27 rational erf approx, |err(erf)| <= 5e-4 (<< bf16 rounding)
__device__ __forceinline__ float fast_gelu(float x) {
    float z = __builtin_fabsf(x) * 0.7071067811865476f;
    float p = 1.f + z*(0.278393f + z*(0.230389f + z*(0.000972f + z*0.078108f)));
    p = p * p;
    p = p * p;
    float e = 1.f - __builtin_amdgcn_rcpf(p);   // erf(|x|/sqrt2)
    float erfv = (x < 0.f) ? -e : e;
    return 0.5f * x * (1.f + erfv);
}

// ---------------- weight fp32 -> bf16 (x stays fp32; GEMM stages+converts it) ------
#define NW4 442368
#define NP4 147456
__global__ void cvt_w(const f4* __restrict__ wq, const f4* __restrict__ wp,
                      bf16x4* __restrict__ wqo, bf16x4* __restrict__ wpo) {
    const long total = NW4 + NP4;
    long stride = (long)gridDim.x * blockDim.x;
    for (long i = (long)blockIdx.x * blockDim.x + threadIdx.x; i < total; i += stride) {
        f4 v; bf16x4* o;
        if (i < NW4) { v = wq[i]; o = wqo + i; }
        else         { v = wp[i - NW4]; o = wpo + (i - NW4); }
        bf16x4 t;
        t[0] = (bf16)v[0]; t[1] = (bf16)v[1]; t[2] = (bf16)v[2]; t[3] = (bf16)v[3];
        *o = t;
    }
}

// map compact grid index (0..19) -> original spatial coord (y or x)
__device__ __forceinline__ int cmap(int i) {
    return ((i + 1) / 3) * 8 + (i + 1) % 3 - 1;
}

// ======== merged Q + KV 128x128 GEMM: A reg-staged fp32->bf16 on the fly ===========
// blocks [0, NBQ):        Q.  M=50176, N=768 (6 bn), GELU, scatter [16][L0][96]
// blocks [NBQ, NBQ+NBKV): KV. M=6400 gathered rows, N=1536 (12 bn), GELU,
//                             compact store [part][b*8+nh][t*400+rr][96]
// LDS per buf: A-bf16 8KB + B-bf16 8KB; 2 bufs = 32KB (+2.8KB epilogue) -> 4 blk/CU.
// A: 4x f32x4 global loads (source chunk-swizzled) -> cvt -> 4x ds_write_b64.
// B: global_load_lds w/ source swizzle (proven R8 path). Frag reads both bf16,
// slot = g ^ ((row>>1)&3). Two-barrier K-loop, counted vmcnt(6), lgkmcnt(0).
__global__ __launch_bounds__(256) void gemm_qkv(
    const float* __restrict__ A, const bf16* __restrict__ Wq,
    const float* __restrict__ bias_q, bf16* __restrict__ OutQ,
    bf16* __restrict__ OutKV)
{
    __shared__ uint8_t sh[34816];    // bufs: [0,16384) and [16384,32768); epilogue tls = all
    const int tid = threadIdx.x;
    const int lane = tid & 63;
    const int w = tid >> 6;
    const int wr = w >> 1, wc = w & 1;
    const int g = lane >> 4;
    const int ar = lane & 15;
    const int K = 768;

    // T1: XCD-chunked bijective swizzle over the merged grid (2952 = 8*369)
    const int nwg = gridDim.x;
    const int q_ = nwg >> 3, r_ = nwg & 7;
    const int xcd = blockIdx.x & 7, off = blockIdx.x >> 3;
    const int swz = (xcd < r_ ? xcd*(q_+1) : r_*(q_+1) + (xcd - r_)*q_) + off;

    const bool isQ = swz < NBQ;
    const int idx = isQ ? swz : swz - NBQ;
    const int NBN = isQ ? 6 : 12;
    const long bm = idx / NBN, bn = idx % NBN;
    const bf16* B = isQ ? Wq : Wq + (size_t)768*768;
    const float* bias = isQ ? bias_q : bias_q + 768;

    f32x4 acc[4][4];
#pragma unroll
    for (int i = 0; i < 4; ++i)
#pragma unroll
        for (int j = 0; j < 4; ++j) acc[i][j] = (f32x4){0.f,0.f,0.f,0.f};

    // ---- A staging geometry: row = s*32 + (tid>>3); q = tid&7 -> dest (slot q>>1, half q&1)
    const int arow_s = tid >> 3;                 // 0..31
    const int qa = tid & 7;
    const int swA = (arow_s >> 1) & 3;           // (row>>1)&3, slab-invariant (s*32>>1 ≡ 0 mod 4)
    const int qsA = ((qa >> 1) ^ swA) * 2 + (qa & 1);   // source f32-quad (swizzled)
    long aoff[4];
#pragma unroll
    for (int s = 0; s < 4; ++s) {
        int rA = (int)bm*128 + s*32 + arow_s;
        if (!isQ) {
            int b = rA / 3200; int r = rA - b*3200;
            int t = r / 400;  int rr = r - t*400;
            int yi = rr / NYC, xi = rr - yi*NYC;
            aoff[s] = ((long)b*L0 + (t*H0 + cmap(yi))*W0 + cmap(xi)) * (long)K;
        } else {
            aoff[s] = (long)rA * K;
        }
    }
    // ---- B staging: row = tid>>2, slot = tid&3, source chunk swizzled
    const int brow_s = tid >> 2;                 // 0..63
    const int csb = (tid & 3) ^ ((tid >> 3) & 3);
    const bf16* Bg = B + (bn*128 + brow_s)*(long)K + csb*8;

    f32x4 rN[4];
    auto loadA = [&](int kt) {
#pragma unroll
        for (int s = 0; s < 4; ++s)
            rN[s] = *(const f32x4*)(A + aoff[s] + kt*32 + qsA*4);
    };
    auto writeA = [&](int buf) {
        bf16* ldsA = (bf16*)(sh + buf*16384);
#pragma unroll
        for (int s = 0; s < 4; ++s) {
            bf16x4 t;
            t[0] = (bf16)rN[s][0]; t[1] = (bf16)rN[s][1];
            t[2] = (bf16)rN[s][2]; t[3] = (bf16)rN[s][3];
            *(bf16x4*)&ldsA[(s*32 + arow_s)*32 + qa*4] = t;   // linear dest: row*64B + qa*8B
        }
    };
    auto gloadB = [&](int buf, int kt) {
#pragma unroll
        for (int s = 0; s < 2; ++s)
            __builtin_amdgcn_global_load_lds(GPTR(Bg + (long)kt*32 + (long)s*64*K),
                LPTR(sh + buf*16384 + 8192 + s*4096 + tid*16), 16, 0, 0);
    };
    auto compute = [&](int buf) {
        const bf16* ldsA = (const bf16*)(sh + buf*16384);
        const bf16* ldsB = (const bf16*)(sh + buf*16384 + 8192);
        bf16x8 af[4], bfr[4];
#pragma unroll
        for (int i = 0; i < 4; ++i) {
            int R = wr*64 + i*16 + ar;
            af[i] = *(const bf16x8*)&ldsA[R*32 + ((g ^ ((R >> 1) & 3))*8)];
        }
#pragma unroll
        for (int j = 0; j < 4; ++j) {
            int R = wc*64 + j*16 + ar;
            bfr[j] = *(const bf16x8*)&ldsB[R*32 + ((g ^ ((R >> 1) & 3))*8)];
        }
        __builtin_amdgcn_s_setprio(1);
#pragma unroll
        for (int i = 0; i < 4; ++i)
#pragma unroll
            for (int j = 0; j < 4; ++j)
                acc[i][j] = __builtin_amdgcn_mfma_f32_16x16x32_bf16(af[i], bfr[j], acc[i][j], 0, 0, 0);
        __builtin_amdgcn_s_setprio(0);
    };

    const int nkt = K / 32;   // 24
    // prologue: stage tile 0 into buf 0
    loadA(0);
    gloadB(0, 0);
    writeA(0);                         // compiler auto-waits rN (vmcnt<=2)
    for (int kt = 0; kt < nkt; ++kt) {
        const int cur = kt & 1, nxt = cur ^ 1;
        const bool pre = (kt + 1 < nkt);
        if (pre) {
            loadA(kt + 1);             // 4 VMEM -> regs (nxt's A)
            gloadB(nxt, kt + 1);       // 2 VMEM -> LDS B nxt (safe: post trailing barrier)
            asm volatile("s_waitcnt vmcnt(6)" ::: "memory");   // cur's B landed
        } else {
            asm volatile("s_waitcnt vmcnt(0)" ::: "memory");
        }
        asm volatile("s_waitcnt lgkmcnt(0)" ::: "memory");     // cur's A ds_writes done
        __builtin_amdgcn_s_barrier();                          // cur fully staged, all waves
        __builtin_amdgcn_sched_barrier(0);
        compute(cur);
        if (pre) writeA(nxt);          // cvt+ds_write under compute's shadow; nxt free since entry
        __builtin_amdgcn_sched_barrier(0);
        __builtin_amdgcn_s_barrier();                          // cur reads retired
    }

    // ---------------- epilogue: LDS transpose + GELU + coalesced bf16x8 stores ------
    __syncthreads();
    bf16* tls = (bf16*)sh;                 // 128 x 136 bf16 = 34816 B
#pragma unroll
    for (int j = 0; j < 4; ++j) {
        const int colb = (int)bn*128 + wc*64 + j*16;
        const int lcol = wc*64 + j*16 + ar;
        const float bcol = bias[colb + ar];
#pragma unroll
        for (int i = 0; i < 4; ++i) {
            int lrow0 = wr*64 + i*16 + (g << 2);
#pragma unroll
            for (int r = 0; r < 4; ++r)
                tls[(lrow0 + r)*136 + lcol] = (bf16)fast_gelu(acc[i][j][r] + bcol);
        }
    }
    __syncthreads();
#pragma unroll
    for (int it = 0; it < 8; ++it) {
        int idx2 = it*256 + tid;
        int mloc = idx2 >> 4;
        int ck = idx2 & 15;
        bf16x8 v = *(const bf16x8*)&tls[mloc*136 + ck*8];
        int m = (int)bm*128 + mloc;
        int col = (int)bn*128 + ck*8;
        if (isQ) {
            int nh = col / HD;
            int c = col - nh*HD;
            int bflag = m >= L0;              // M = 2*L0
            int l = m - (bflag ? L0 : 0);
            size_t addr = ((size_t)(bflag*8 + nh)*L0 + l)*HD + c;
            *(bf16x8*)&OutQ[addr] = v;
        } else {
            int part = col / 768;
            int cb = col - part*768;
            int nh = cb / HD;
            int c = cb - nh*HD;
            int b = m / 3200; int r = m - b*3200;   // r = t*400 + rr
            size_t addr = ((size_t)(part*16 + b*8 + nh)*3200 + r)*HD + c;
            *(bf16x8*)&OutKV[addr] = v;
        }
    }
}

// ---------------- 128x128 bf16-A GEMM — proj only --------------------------------
__global__ __launch_bounds__(256) void gemm_proj(
    const bf16* __restrict__ A, const bf16* __restrict__ B,
    const float* __restrict__ bias, float* __restrict__ Out,
    int M, int N, int K, int NBN)
{
    __shared__ bf16 sh[2*16384];
    const int tid = threadIdx.x;
    const int lane = tid & 63;
    const int w = tid >> 6;
    const int wr = w >> 1, wc = w & 1;

    const int nwg = gridDim.x;
    const int q_ = nwg >> 3, r_ = nwg & 7;
    const int xcd = blockIdx.x & 7, off = blockIdx.x >> 3;
    const int swz = (xcd < r_ ? xcd*(q_+1) : r_*(q_+1) + (xcd - r_)*q_) + off;
    const long bn = swz % NBN, bm = swz / NBN;

    f32x4 acc[4][4];
#pragma unroll
    for (int i = 0; i < 4; ++i)
#pragma unroll
        for (int j = 0; j < 4; ++j) acc[i][j] = (f32x4){0.f,0.f,0.f,0.f};

    const int trow = tid >> 3;
    const int tchunk = (tid & 7) ^ (trow & 7);
    const bf16* Ag = A + (bm*128 + trow)*(long)K + tchunk*8;
    const bf16* Bg = B + (bn*128 + trow)*(long)K + tchunk*8;

    const int arow = lane & 15;
    const int g8 = (lane >> 4) * 8;
    const int aswz = (arow & 7) * 8;

    auto stage = [&](int buf, int kt) {
        bf16* ldsA = sh + buf*16384;
        bf16* ldsB = sh + buf*16384 + 8192;
#pragma unroll
        for (int s = 0; s < 4; ++s) {
            __builtin_amdgcn_global_load_lds(GPTR(Ag + (long)kt*64 + (long)s*32*K),
                                             LPTR(ldsA + s*2048 + tid*8), 16, 0, 0);
            __builtin_amdgcn_global_load_lds(GPTR(Bg + (long)kt*64 + (long)s*32*K),
                                             LPTR(ldsB + s*2048 + tid*8), 16, 0, 0);
        }
    };
    auto compute = [&](int buf) {
        const bf16* ldsA = sh + buf*16384;
        const bf16* ldsB = sh + buf*16384 + 8192;
#pragma unroll
        for (int kk = 0; kk < 2; ++kk) {
            bf16x8 af[4], bfr[4];
#pragma unroll
            for (int i = 0; i < 4; ++i)
                af[i] = *(const bf16x8*)&ldsA[(wr*64 + i*16 + arow)*64 + ((kk*32 + g8) ^ aswz)];
#pragma unroll
            for (int j = 0; j < 4; ++j)
                bfr[j] = *(const bf16x8*)&ldsB[(wc*64 + j*16 + arow)*64 + ((kk*32 + g8) ^ aswz)];
            __builtin_amdgcn_s_setprio(1);
#pragma unroll
            for (int i = 0; i < 4; ++i)
#pragma unroll
                for (int j = 0; j < 4; ++j)
                    acc[i][j] = __builtin_amdgcn_mfma_f32_16x16x32_bf16(af[i], bfr[j], acc[i][j], 0, 0, 0);
            __builtin_amdgcn_s_setprio(0);
        }
    };

    const int nkt = K / 64;
    stage(0, 0);
    for (int kt = 0; kt < nkt; ++kt) {
        if (kt + 1 < nkt) {
            stage((kt + 1) & 1, kt + 1);
            asm volatile("s_waitcnt vmcnt(8)" ::: "memory");
        } else {
            asm volatile("s_waitcnt vmcnt(0)" ::: "memory");
        }
        __builtin_amdgcn_s_barrier();
        __builtin_amdgcn_sched_barrier(0);
        compute(kt & 1);
        __builtin_amdgcn_sched_barrier(0);
        __builtin_amdgcn_s_barrier();
    }

#pragma unroll
    for (int j = 0; j < 4; ++j) {
        const int col = (int)bn*128 + wc*64 + j*16 + (lane & 15);
        const float bcol = bias[col];
#pragma unroll
        for (int i = 0; i < 4; ++i) {
            int row0 = (int)bm*128 + wr*64 + i*16 + ((lane>>4)<<2);
#pragma unroll
            for (int r = 0; r < 4; ++r)
                Out[(size_t)(row0 + r)*N + col] = acc[i][j][r] + bcol;
        }
    }
}

// ---------------- merged depthwise conv3d: q-path + kv-path in one dispatch --------
__global__ __launch_bounds__(256) void dwconv_all(
    const bf16* __restrict__ qin, const bf16* __restrict__ kv,
    const float* __restrict__ wq, const float* __restrict__ wk,
    const float* __restrict__ wv, bf16* __restrict__ qout,
    bf16* __restrict__ kout, bf16* __restrict__ vtout)
{
    __shared__ float lw[27*HD];
    const int blk = blockIdx.x;
    if (blk < 588) {
        for (int i = threadIdx.x; i < 27*HD; i += 256) {
            int c = i / 27, tap = i % 27;
            lw[tap*HD + c] = wq[i];
        }
        __syncthreads();
        int idx = blk*256 + threadIdx.x;
        if (idx >= 16*HP_Q*WP_Q*12) return;
        int c8 = idx % 12;
        int p = idx / 12;
        int xo = p % WP_Q;
        int yo = (p / WP_Q) % HP_Q;
        int bh = p / (WP_Q*HP_Q);
        const bf16* ip = qin + (size_t)bh * L0 * HD + c8*8;

        float acc[T0][8];
#pragma unroll
        for (int t = 0; t < T0; ++t)
#pragma unroll
            for (int j = 0; j < 8; ++j) acc[t][j] = 0.f;

#pragma unroll
        for (int dy = 0; dy < 3; ++dy) {
            int y = yo*2 + dy - 1;
            if ((unsigned)y >= (unsigned)H0) continue;
#pragma unroll
            for (int dx = 0; dx < 3; ++dx) {
                int x = xo*2 + dx - 1;
                if ((unsigned)x >= (unsigned)W0) continue;
                float wreg[3][8];
#pragma unroll
                for (int dt = 0; dt < 3; ++dt)
#pragma unroll
                    for (int j = 0; j < 8; ++j)
                        wreg[dt][j] = lw[(dt*9 + dy*3 + dx)*HD + c8*8 + j];
                const bf16* colp = ip + ((size_t)(y*W0 + x))*HD;
#pragma unroll
                for (int t = 0; t < T0; ++t) {
                    bf16x8 v = *(const bf16x8*)(colp + (size_t)t*H0*W0*HD);
                    float f[8];
#pragma unroll
                    for (int j = 0; j < 8; ++j) f[j] = (float)v[j];
#pragma unroll
                    for (int dt = 0; dt < 3; ++dt) {
                        int to = t - dt + 1;
                        if (to < 0 || to >= T0) continue;
#pragma unroll
                        for (int j = 0; j < 8; ++j)
                            acc[to][j] += wreg[dt][j] * f[j];
                    }
                }
            }
        }

#pragma unroll
        for (int to = 0; to < T0; ++to) {
            int l = (to*HP_Q + yo)*WP_Q + xo;
            bf16x8 ov;
#pragma unroll
            for (int j = 0; j < 8; ++j) ov[j] = (bf16)acc[to][j];
            *(bf16x8*)&qout[((size_t)bh*LQ + l)*HD + c8*8] = ov;
        }
        return;
    }

    const int kb = blk - 588;          // 0..79
    const int seg = kb / 40;
    const int lb  = kb % 40;
    const float* w = seg ? wv : wk;
    const bf16* in = kv + (size_t)seg * 16 * 3200 * HD;
    for (int i = threadIdx.x; i < 27*HD; i += 256) {
        int c = i / 27, tap = i % 27;
        lw[tap*HD + c] = w[i];
    }
    __syncthreads();

    if (lb >= 37) {   // pad-zero blocks
        int pid = (lb - 37)*256 + threadIdx.x;
        if (seg == 0) {
            for (int e = pid; e < 16*24*96; e += 768) {
                int bh = e / (24*96); int rem = e - bh*24*96;
                int l = LK + rem / 96; int c = rem % 96;
                kout[((size_t)bh*LKP + l)*HD + c] = (bf16)0.f;
            }
        } else {
            for (int e = pid; e < 16*96*24; e += 768) {
                int bh = e / (96*24); int rem = e - bh*96*24;
                int c = rem / 24; int l = LK + rem % 24;
                vtout[((size_t)bh*HD + c)*LKP + l] = (bf16)0.f;
            }
        }
        return;
    }

    int idx = lb*256 + threadIdx.x;
    if (idx >= 16*HP_K*WP_K*12) return;
    int c8 = idx % 12;
    int p = idx / 12;
    int xo = p % WP_K;
    int yo = (p / WP_K) % HP_K;
    int bh = p / (WP_K*HP_K);
    const bf16* ip = in + (size_t)bh * 3200 * HD + c8*8;

    float acc[T0][8];
#pragma unroll
    for (int t = 0; t < T0; ++t)
#pragma unroll
        for (int j = 0; j < 8; ++j) acc[t][j] = 0.f;

#pragma unroll
    for (int dy = 0; dy < 3; ++dy) {
        int yi = 3*yo + dy - 1;
        if ((unsigned)yi >= (unsigned)NYC) continue;
#pragma unroll
        for (int dx = 0; dx < 3; ++dx) {
            int xi = 3*xo + dx - 1;
            if ((unsigned)xi >= (unsigned)NYC) continue;
            float wreg[3][8];
#pragma unroll
            for (int dt = 0; dt < 3; ++dt)
#pragma unroll
                for (int j = 0; j < 8; ++j)
                    wreg[dt][j] = lw[(dt*9 + dy*3 + dx)*HD + c8*8 + j];
            const bf16* colp = ip + ((size_t)(yi*NYC + xi))*HD;
#pragma unroll
            for (int t = 0; t < T0; ++t) {
                bf16x8 v = *(const bf16x8*)(colp + (size_t)t*400*HD);
                float f[8];
#pragma unroll
                for (int j = 0; j < 8; ++j) f[j] = (float)v[j];
#pragma unroll
                for (int dt = 0; dt < 3; ++dt) {
                    int to = t - dt + 1;
                    if (to < 0 || to >= T0) continue;
#pragma unroll
                    for (int j = 0; j < 8; ++j)
                        acc[to][j] += wreg[dt][j] * f[j];
                }
            }
        }
    }

#pragma unroll
    for (int to = 0; to < T0; ++to) {
        int l = (to*HP_K + yo)*WP_K + xo;
        if (seg == 1) {
#pragma unroll
            for (int j = 0; j < 8; ++j)
                vtout[((size_t)bh*HD + c8*8 + j)*LKP + l] = (bf16)acc[to][j];
        } else {
            bf16x8 ov;
#pragma unroll
            for (int j = 0; j < 8; ++j) ov[j] = (bf16)acc[to][j];
            *(bf16x8*)&kout[((size_t)bh*LKP + l)*HD + c8*8] = ov;
        }
    }
}

// ---------------- MFMA attention: block = (b,h) x 64 q rows, wave = 16 q rows -------
__global__ __launch_bounds__(256) void attn_mfma(
    const bf16* __restrict__ q, const bf16* __restrict__ k,
    const bf16* __restrict__ vt, bf16* __restrict__ out)
{
    const int tid = threadIdx.x;
    const int lane = tid & 63;
    const int w = tid >> 6;
    const int col = lane & 15;
    const int g = lane >> 4;
    const int blk = blockIdx.x;
    const int qblk = blk % (LQ/64);
    const int bh = blk / (LQ/64);
    const int q0 = qblk*64 + w*16;

    const bf16* Qp  = q  + ((size_t)bh*LQ + q0)*HD;
    const bf16* Kp  = k  + (size_t)bh*LKP*HD;
    const bf16* VTp = vt + (size_t)bh*HD*LKP;

    bf16x8 qf[3];
#pragma unroll
    for (int c = 0; c < 3; ++c)
        qf[c] = *(const bf16x8*)&Qp[(size_t)col*HD + c*32 + g*8];

    f32x4 o[6];
#pragma unroll
    for (int t = 0; t < 6; ++t) o[t] = (f32x4){0.f,0.f,0.f,0.f};
    float lsum = 0.f;

    for (int kc = 0; kc < LKP/32; ++kc) {
        const int kvb = kc*32;
        uint32_t P[2][2];
#pragma unroll
        for (int s = 0; s < 2; ++s) {
            f32x4 acc = (f32x4){0.f,0.f,0.f,0.f};
#pragma unroll
            for (int c = 0; c < 3; ++c) {
                bf16x8 kf = *(const bf16x8*)&Kp[(size_t)(kvb + s*16 + col)*HD + c*32 + g*8];
                acc = __builtin_amdgcn_mfma_f32_16x16x32_bf16(kf, qf[c], acc, 0, 0, 0);
            }
            bf16x4 pb;
#pragma unroll
            for (int r = 0; r < 4; ++r) {
                int kv = kvb + s*16 + g*4 + r;
                float p = (kv < LK) ? __expf(acc[r]*SCALE) : 0.f;
                lsum += p;
                pb[r] = (bf16)p;
            }
            union { bf16x4 v; uint32_t u[2]; } pk; pk.v = pb;
            P[s][0] = pk.u[0]; P[s][1] = pk.u[1];
        }
        uint32_t sa0 = (g < 2) ? P[1][0] : P[0][0];
        uint32_t sa1 = (g < 2) ? P[1][1] : P[0][1];
        uint32_t tb0 = (g < 2) ? P[0][0] : P[1][0];
        uint32_t tb1 = (g < 2) ? P[0][1] : P[1][1];
        uint32_t R32_0 = (uint32_t)__shfl_xor((int)sa0, 32);
        uint32_t R32_1 = (uint32_t)__shfl_xor((int)sa1, 32);
        uint32_t R48_0 = (uint32_t)__shfl_xor((int)sa0, 48);
        uint32_t R48_1 = (uint32_t)__shfl_xor((int)sa1, 48);
        uint32_t R16_0 = (uint32_t)__shfl_xor((int)tb0, 16);
        uint32_t R16_1 = (uint32_t)__shfl_xor((int)tb1, 16);
        union { uint32_t u[4]; bf16x8 v; } pf;
        pf.u[0] = (g == 0) ? P[0][0] : (g == 1) ? R48_0 : (g == 2) ? R32_0 : R16_0;
        pf.u[1] = (g == 0) ? P[0][1] : (g == 1) ? R48_1 : (g == 2) ? R32_1 : R16_1;
        pf.u[2] = (g == 0) ? R16_0 : (g == 1) ? R32_0 : (g == 2) ? R48_0 : P[1][0];
        pf.u[3] = (g == 0) ? R16_1 : (g == 1) ? R32_1 : (g == 2) ? R48_1 : P[1][1];
#pragma unroll
        for (int t = 0; t < 6; ++t) {
            bf16x8 vf = *(const bf16x8*)&VTp[(size_t)(t*16 + col)*LKP + kvb + g*8];
            o[t] = __builtin_amdgcn_mfma_f32_16x16x32_bf16(vf, pf.v, o[t], 0, 0, 0);
        }
    }

    lsum += __shfl_xor(lsum, 16);
    lsum += __shfl_xor(lsum, 32);
    float inv = 1.f / lsum;

    const int b = bh >> 3, nh = bh & 7;
    size_t obase = ((size_t)b*LQ + q0 + col)*CDIM + (size_t)nh*HD;
#pragma unroll
    for (int t = 0; t < 6; ++t) {
        bf16x4 qres = *(const bf16x4*)&Qp[(size_t)col*HD + t*16 + g*4];
        bf16x4 ov;
#pragma unroll
        for (int r = 0; r < 4; ++r)
            ov[r] = (bf16)(o[t][r]*inv + (float)qres[r]);
        *(bf16x4*)&out[obase + t*16 + g*4] = ov;
    }
}

extern "C" void kernel_launch(void* const* d_in, const int* in_sizes, int n_in,
                              void* d_out, int out_size, void* d_ws, size_t ws_size,
                              hipStream_t stream) {
    const float* x      = (const float*)d_in[0];
    const float* qkv_w  = (const float*)d_in[1];
    const float* qkv_b  = (const float*)d_in[2];
    const float* proj_w = (const float*)d_in[3];
    const float* proj_b = (const float*)d_in[4];
    const float* pq_w   = (const float*)d_in[5];
    const float* pk_w   = (const float*)d_in[6];
    const float* pv_w   = (const float*)d_in[7];

    uint8_t* ws = (uint8_t*)d_ws;
    bf16* qg_out   = (bf16*)(ws);                  // 77,070,336 B  [16][L0][96] (GELU'd Q)
    bf16* kv_c     = (bf16*)(ws +  77070336);      // 19,660,800 B  [2][16][3200][96]
    bf16* wqkv_bf  = (bf16*)(ws +  96731136);      // 3,538,944 B
    bf16* wproj_bf = (bf16*)(ws + 100270080);      // 1,179,648 B
    bf16* q_bf     = (bf16*)(ws + 101449728);      // 19,267,584 B  [16][6272][96]
    bf16* k_bf     = (bf16*)(ws + 120717312);      // 1,277,952 B   [16][416][96]
    bf16* vt_bf    = (bf16*)(ws + 121995264);      // 1,277,952 B   [16][96][416]
    bf16* attn_o   = (bf16*)(ws + 123273216);      // 19,267,584 B -> end 142,540,800

    cvt_w<<<576, 256, 0, stream>>>((const f4*)qkv_w, (const f4*)proj_w,
                                   (bf16x4*)wqkv_bf, (bf16x4*)wproj_bf);

    // merged Q + KV GEMM (2952 blocks, one dispatch, reg-staged A cvt)
    gemm_qkv<<<NBQ + NBKV, 256, 0, stream>>>(x, wqkv_bf, qkv_b, qg_out, kv_c);

    // merged convs (q + k + v + pad-zeroing, one dispatch)
    dwconv_all<<<668, 256, 0, stream>>>(qg_out, kv_c, pq_w, pk_w, pv_w,
                                        q_bf, k_bf, vt_bf);

    attn_mfma<<<16*(LQ/64), 256, 0, stream>>>(q_bf, k_bf, vt_bf, attn_o);

    gemm_proj<<<6*98, 256, 0, stream>>>(
        attn_o, wproj_bf, proj_b, (float*)d_out, 12544, 768, 768, 6);
}

// Round 13
// 283.457 us; speedup vs baseline: 1.7868x; 1.0380x over previous
//
#include <hip/hip_runtime.h>
#include <cstdint>

#define NH 8
#define HD 96
#define CDIM 768
#define BQ 2
#define T0 8
#define H0 56
#define W0 56
#define L0 (T0*H0*W0)     // 25088
#define HP_Q 28
#define WP_Q 28
#define LQ (T0*HP_Q*WP_Q) // 6272
#define HP_K 7
#define WP_K 7
#define LK (T0*HP_K*WP_K) // 392
#define LKP 416           // kv padded to multiple of 32
#define SCALE 0.10206207261596577f
#define NYC 20
#define MKV 6400          // 2*8*400 gathered kv rows (50 x 128)
#define NBQ 2352          // Q-gemm blocks: 392 bm x 6 bn
#define NBKV 600          // KV-gemm blocks: 50 bm x 12 bn

typedef __bf16 bf16;
typedef bf16 bf16x4 __attribute__((ext_vector_type(4)));
typedef bf16 bf16x8 __attribute__((ext_vector_type(8)));
typedef float f32x4 __attribute__((ext_vector_type(4)));
typedef float f4 __attribute__((ext_vector_type(4)));

#define GPTR(x) ((const __attribute__((address_space(1))) void*)(x))
#define LPTR(x) ((__attribute__((address_space(3))) void*)(x))

// fast erf-GELU: A&S 7.1.27 rational erf approx, |err(erf)| <= 5e-4 (<< bf16 rounding)
__device__ __forceinline__ float fast_gelu(float x) {
    float z = __builtin_fabsf(x) * 0.7071067811865476f;
    float p = 1.f + z*(0.278393f + z*(0.230389f + z*(0.000972f + z*0.078108f)));
    p = p * p;
    p = p * p;
    float e = 1.f - __builtin_amdgcn_rcpf(p);   // erf(|x|/sqrt2)
    float erfv = (x < 0.f) ? -e : e;
    return 0.5f * x * (1.f + erfv);
}

// ---------------- fused fp32 -> bf16 conversion (x, qkv_w, proj_w) -----------------
#define NX4 9633792
#define NW4 442368
#define NP4 147456
__global__ void cvt_all(const f4* __restrict__ x, const f4* __restrict__ wq,
                        const f4* __restrict__ wp, bf16x4* __restrict__ xo,
                        bf16x4* __restrict__ wqo, bf16x4* __restrict__ wpo) {
    const long total = (long)NX4 + NW4 + NP4;
    long stride = (long)gridDim.x * blockDim.x;
    for (long i = (long)blockIdx.x * blockDim.x + threadIdx.x; i < total; i += stride) {
        f4 v; bf16x4* o;
        if (i < NX4)            { v = x[i];              o = xo + i; }
        else if (i < NX4 + NW4) { v = wq[i - NX4];       o = wqo + (i - NX4); }
        else                    { v = wp[i - NX4 - NW4]; o = wpo + (i - NX4 - NW4); }
        bf16x4 t;
        t[0] = (bf16)v[0]; t[1] = (bf16)v[1]; t[2] = (bf16)v[2]; t[3] = (bf16)v[3];
        *o = t;
    }
}

// map compact grid index (0..19) -> original spatial coord (y or x)
__device__ __forceinline__ int cmap(int i) {
    return ((i + 1) / 3) * 8 + (i + 1) % 3 - 1;
}

// ======== merged Q + KV 128x128 GEMM, bf16 A via global_load_lds (R8 structure) ====
// blocks [0, NBQ):        Q.  M=50176, N=768 (6 bn), GELU, scatter [16][L0][96]
// blocks [NBQ, NBQ+NBKV): KV. M=6400 gathered rows, N=1536 (12 bn), GELU,
//                             compact store [part][b*8+nh][t*400+rr][96]
// BK=64 dbuf (64KB), T1 XCD swizzle, T2 source-side chunk swizzle, counted vmcnt(8),
// two-barrier K-loop — the R8-measured 600 TF configuration, verbatim.
__global__ __launch_bounds__(256) void gemm_qkv(
    const bf16* __restrict__ A, const bf16* __restrict__ Wq,
    const float* __restrict__ bias_q, bf16* __restrict__ OutQ,
    bf16* __restrict__ OutKV)
{
    __shared__ bf16 sh[2*16384];     // [buf][A:8192|B:8192] elements = 64 KiB
    const int tid = threadIdx.x;
    const int lane = tid & 63;
    const int w = tid >> 6;
    const int wr = w >> 1, wc = w & 1;
    const int K = 768;

    // T1: XCD-chunked bijective swizzle over the merged grid (2952 = 8*369)
    const int nwg = gridDim.x;
    const int q_ = nwg >> 3, r_ = nwg & 7;
    const int xcd = blockIdx.x & 7, off = blockIdx.x >> 3;
    const int swz = (xcd < r_ ? xcd*(q_+1) : r_*(q_+1) + (xcd - r_)*q_) + off;

    const bool isQ = swz < NBQ;
    const int idx = isQ ? swz : swz - NBQ;
    const int NBN = isQ ? 6 : 12;
    const long bm = idx / NBN, bn = idx % NBN;
    const bf16* B = isQ ? Wq : Wq + (size_t)768*768;
    const float* bias = isQ ? bias_q : bias_q + 768;

    f32x4 acc[4][4];
#pragma unroll
    for (int i = 0; i < 4; ++i)
#pragma unroll
        for (int j = 0; j < 4; ++j) acc[i][j] = (f32x4){0.f,0.f,0.f,0.f};

    const int trow = tid >> 3;                       // 0..31
    const int tchunk = (tid & 7) ^ (trow & 7);       // inverse swizzle on SOURCE

    long aoff[4];
#pragma unroll
    for (int s = 0; s < 4; ++s) {
        int rA = (int)bm*128 + s*32 + trow;
        if (!isQ) {
            int b = rA / 3200; int r = rA - b*3200;
            int t = r / 400;  int rr = r - t*400;
            int yi = rr / NYC, xi = rr - yi*NYC;
            aoff[s] = ((long)b*L0 + (t*H0 + cmap(yi))*W0 + cmap(xi)) * (long)K;
        } else {
            aoff[s] = (long)rA * K;
        }
    }
    const bf16* Bg = B + (bn*128 + trow)*(long)K + tchunk*8;

    const int arow = lane & 15;
    const int g8 = (lane >> 4) * 8;
    const int aswz = (arow & 7) * 8;                 // element-XOR for ds_read

    auto stage = [&](int buf, int kt) {
        bf16* ldsA = sh + buf*16384;
        bf16* ldsB = sh + buf*16384 + 8192;
#pragma unroll
        for (int s = 0; s < 4; ++s) {
            __builtin_amdgcn_global_load_lds(GPTR(A + aoff[s] + kt*64 + tchunk*8),
                                             LPTR(ldsA + s*2048 + tid*8), 16, 0, 0);
            __builtin_amdgcn_global_load_lds(GPTR(Bg + (long)kt*64 + (long)s*32*K),
                                             LPTR(ldsB + s*2048 + tid*8), 16, 0, 0);
        }
    };
    auto compute = [&](int buf) {
        const bf16* ldsA = sh + buf*16384;
        const bf16* ldsB = sh + buf*16384 + 8192;
#pragma unroll
        for (int kk = 0; kk < 2; ++kk) {
            bf16x8 af[4], bfr[4];
#pragma unroll
            for (int i = 0; i < 4; ++i)
                af[i] = *(const bf16x8*)&ldsA[(wr*64 + i*16 + arow)*64 + ((kk*32 + g8) ^ aswz)];
#pragma unroll
            for (int j = 0; j < 4; ++j)
                bfr[j] = *(const bf16x8*)&ldsB[(wc*64 + j*16 + arow)*64 + ((kk*32 + g8) ^ aswz)];
            __builtin_amdgcn_s_setprio(1);
#pragma unroll
            for (int i = 0; i < 4; ++i)
#pragma unroll
                for (int j = 0; j < 4; ++j)
                    acc[i][j] = __builtin_amdgcn_mfma_f32_16x16x32_bf16(af[i], bfr[j], acc[i][j], 0, 0, 0);
            __builtin_amdgcn_s_setprio(0);
        }
    };

    const int nkt = K / 64;   // 12
    stage(0, 0);
    for (int kt = 0; kt < nkt; ++kt) {
        if (kt + 1 < nkt) {
            stage((kt + 1) & 1, kt + 1);
            asm volatile("s_waitcnt vmcnt(8)" ::: "memory");   // kt's 8 loads landed
        } else {
            asm volatile("s_waitcnt vmcnt(0)" ::: "memory");
        }
        __builtin_amdgcn_s_barrier();
        __builtin_amdgcn_sched_barrier(0);
        compute(kt & 1);
        __builtin_amdgcn_sched_barrier(0);
        __builtin_amdgcn_s_barrier();
    }

    // ---------------- epilogue: LDS transpose + GELU + coalesced bf16x8 stores ------
    __syncthreads();
    bf16* tls = sh;                        // 128 x 136 bf16 = 34.8 KB
#pragma unroll
    for (int j = 0; j < 4; ++j) {
        const int colb = (int)bn*128 + wc*64 + j*16;
        const int lcol = wc*64 + j*16 + (lane & 15);
        const float bcol = bias[colb + (lane & 15)];
#pragma unroll
        for (int i = 0; i < 4; ++i) {
            int lrow0 = wr*64 + i*16 + ((lane>>4)<<2);
#pragma unroll
            for (int r = 0; r < 4; ++r)
                tls[(lrow0 + r)*136 + lcol] = (bf16)fast_gelu(acc[i][j][r] + bcol);
        }
    }
    __syncthreads();
#pragma unroll
    for (int it = 0; it < 8; ++it) {
        int idx2 = it*256 + tid;
        int mloc = idx2 >> 4;
        int ck = idx2 & 15;
        bf16x8 v = *(const bf16x8*)&tls[mloc*136 + ck*8];
        int m = (int)bm*128 + mloc;
        int col = (int)bn*128 + ck*8;
        if (isQ) {
            int nh = col / HD;
            int c = col - nh*HD;
            int bflag = m >= L0;              // M = 2*L0
            int l = m - (bflag ? L0 : 0);
            size_t addr = ((size_t)(bflag*8 + nh)*L0 + l)*HD + c;
            *(bf16x8*)&OutQ[addr] = v;
        } else {
            int part = col / 768;
            int cb = col - part*768;
            int nh = cb / HD;
            int c = cb - nh*HD;
            int b = m / 3200; int r = m - b*3200;   // r = t*400 + rr
            size_t addr = ((size_t)(part*16 + b*8 + nh)*3200 + r)*HD + c;
            *(bf16x8*)&OutKV[addr] = v;
        }
    }
}

// ---------------- 128x128 bf16-A GEMM — proj only --------------------------------
__global__ __launch_bounds__(256) void gemm_proj(
    const bf16* __restrict__ A, const bf16* __restrict__ B,
    const float* __restrict__ bias, float* __restrict__ Out,
    int M, int N, int K, int NBN)
{
    __shared__ bf16 sh[2*16384];
    const int tid = threadIdx.x;
    const int lane = tid & 63;
    const int w = tid >> 6;
    const int wr = w >> 1, wc = w & 1;

    const int nwg = gridDim.x;
    const int q_ = nwg >> 3, r_ = nwg & 7;
    const int xcd = blockIdx.x & 7, off = blockIdx.x >> 3;
    const int swz = (xcd < r_ ? xcd*(q_+1) : r_*(q_+1) + (xcd - r_)*q_) + off;
    const long bn = swz % NBN, bm = swz / NBN;

    f32x4 acc[4][4];
#pragma unroll
    for (int i = 0; i < 4; ++i)
#pragma unroll
        for (int j = 0; j < 4; ++j) acc[i][j] = (f32x4){0.f,0.f,0.f,0.f};

    const int trow = tid >> 3;
    const int tchunk = (tid & 7) ^ (trow & 7);
    const bf16* Ag = A + (bm*128 + trow)*(long)K + tchunk*8;
    const bf16* Bg = B + (bn*128 + trow)*(long)K + tchunk*8;

    const int arow = lane & 15;
    const int g8 = (lane >> 4) * 8;
    const int aswz = (arow & 7) * 8;

    auto stage = [&](int buf, int kt) {
        bf16* ldsA = sh + buf*16384;
        bf16* ldsB = sh + buf*16384 + 8192;
#pragma unroll
        for (int s = 0; s < 4; ++s) {
            __builtin_amdgcn_global_load_lds(GPTR(Ag + (long)kt*64 + (long)s*32*K),
                                             LPTR(ldsA + s*2048 + tid*8), 16, 0, 0);
            __builtin_amdgcn_global_load_lds(GPTR(Bg + (long)kt*64 + (long)s*32*K),
                                             LPTR(ldsB + s*2048 + tid*8), 16, 0, 0);
        }
    };
    auto compute = [&](int buf) {
        const bf16* ldsA = sh + buf*16384;
        const bf16* ldsB = sh + buf*16384 + 8192;
#pragma unroll
        for (int kk = 0; kk < 2; ++kk) {
            bf16x8 af[4], bfr[4];
#pragma unroll
            for (int i = 0; i < 4; ++i)
                af[i] = *(const bf16x8*)&ldsA[(wr*64 + i*16 + arow)*64 + ((kk*32 + g8) ^ aswz)];
#pragma unroll
            for (int j = 0; j < 4; ++j)
                bfr[j] = *(const bf16x8*)&ldsB[(wc*64 + j*16 + arow)*64 + ((kk*32 + g8) ^ aswz)];
            __builtin_amdgcn_s_setprio(1);
#pragma unroll
            for (int i = 0; i < 4; ++i)
#pragma unroll
                for (int j = 0; j < 4; ++j)
                    acc[i][j] = __builtin_amdgcn_mfma_f32_16x16x32_bf16(af[i], bfr[j], acc[i][j], 0, 0, 0);
            __builtin_amdgcn_s_setprio(0);
        }
    };

    const int nkt = K / 64;
    stage(0, 0);
    for (int kt = 0; kt < nkt; ++kt) {
        if (kt + 1 < nkt) {
            stage((kt + 1) & 1, kt + 1);
            asm volatile("s_waitcnt vmcnt(8)" ::: "memory");
        } else {
            asm volatile("s_waitcnt vmcnt(0)" ::: "memory");
        }
        __builtin_amdgcn_s_barrier();
        __builtin_amdgcn_sched_barrier(0);
        compute(kt & 1);
        __builtin_amdgcn_sched_barrier(0);
        __builtin_amdgcn_s_barrier();
    }

#pragma unroll
    for (int j = 0; j < 4; ++j) {
        const int col = (int)bn*128 + wc*64 + j*16 + (lane & 15);
        const float bcol = bias[col];
#pragma unroll
        for (int i = 0; i < 4; ++i) {
            int row0 = (int)bm*128 + wr*64 + i*16 + ((lane>>4)<<2);
#pragma unroll
            for (int r = 0; r < 4; ++r)
                Out[(size_t)(row0 + r)*N + col] = acc[i][j][r] + bcol;
        }
    }
}

// ---------------- merged depthwise conv3d: q-path + kv-path in one dispatch --------
__global__ __launch_bounds__(256) void dwconv_all(
    const bf16* __restrict__ qin, const bf16* __restrict__ kv,
    const float* __restrict__ wq, const float* __restrict__ wk,
    const float* __restrict__ wv, bf16* __restrict__ qout,
    bf16* __restrict__ kout, bf16* __restrict__ vtout)
{
    __shared__ float lw[27*HD];
    const int blk = blockIdx.x;
    if (blk < 588) {
        for (int i = threadIdx.x; i < 27*HD; i += 256) {
            int c = i / 27, tap = i % 27;
            lw[tap*HD + c] = wq[i];
        }
        __syncthreads();
        int idx = blk*256 + threadIdx.x;
        if (idx >= 16*HP_Q*WP_Q*12) return;
        int c8 = idx % 12;
        int p = idx / 12;
        int xo = p % WP_Q;
        int yo = (p / WP_Q) % HP_Q;
        int bh = p / (WP_Q*HP_Q);
        const bf16* ip = qin + (size_t)bh * L0 * HD + c8*8;

        float acc[T0][8];
#pragma unroll
        for (int t = 0; t < T0; ++t)
#pragma unroll
            for (int j = 0; j < 8; ++j) acc[t][j] = 0.f;

#pragma unroll
        for (int dy = 0; dy < 3; ++dy) {
            int y = yo*2 + dy - 1;
            if ((unsigned)y >= (unsigned)H0) continue;
#pragma unroll
            for (int dx = 0; dx < 3; ++dx) {
                int x = xo*2 + dx - 1;
                if ((unsigned)x >= (unsigned)W0) continue;
                float wreg[3][8];
#pragma unroll
                for (int dt = 0; dt < 3; ++dt)
#pragma unroll
                    for (int j = 0; j < 8; ++j)
                        wreg[dt][j] = lw[(dt*9 + dy*3 + dx)*HD + c8*8 + j];
                const bf16* colp = ip + ((size_t)(y*W0 + x))*HD;
#pragma unroll
                for (int t = 0; t < T0; ++t) {
                    bf16x8 v = *(const bf16x8*)(colp + (size_t)t*H0*W0*HD);
                    float f[8];
#pragma unroll
                    for (int j = 0; j < 8; ++j) f[j] = (float)v[j];
#pragma unroll
                    for (int dt = 0; dt < 3; ++dt) {
                        int to = t - dt + 1;
                        if (to < 0 || to >= T0) continue;
#pragma unroll
                        for (int j = 0; j < 8; ++j)
                            acc[to][j] += wreg[dt][j] * f[j];
                    }
                }
            }
        }

#pragma unroll
        for (int to = 0; to < T0; ++to) {
            int l = (to*HP_Q + yo)*WP_Q + xo;
            bf16x8 ov;
#pragma unroll
            for (int j = 0; j < 8; ++j) ov[j] = (bf16)acc[to][j];
            *(bf16x8*)&qout[((size_t)bh*LQ + l)*HD + c8*8] = ov;
        }
        return;
    }

    const int kb = blk - 588;          // 0..79
    const int seg = kb / 40;
    const int lb  = kb % 40;
    const float* w = seg ? wv : wk;
    const bf16* in = kv + (size_t)seg * 16 * 3200 * HD;
    for (int i = threadIdx.x; i < 27*HD; i += 256) {
        int c = i / 27, tap = i % 27;
        lw[tap*HD + c] = w[i];
    }
    __syncthreads();

    if (lb >= 37) {   // pad-zero blocks
        int pid = (lb - 37)*256 + threadIdx.x;
        if (seg == 0) {
            for (int e = pid; e < 16*24*96; e += 768) {
                int bh = e / (24*96); int rem = e - bh*24*96;
                int l = LK + rem / 96; int c = rem % 96;
                kout[((size_t)bh*LKP + l)*HD + c] = (bf16)0.f;
            }
        } else {
            for (int e = pid; e < 16*96*24; e += 768) {
                int bh = e / (96*24); int rem = e - bh*96*24;
                int c = rem / 24; int l = LK + rem % 24;
                vtout[((size_t)bh*HD + c)*LKP + l] = (bf16)0.f;
            }
        }
        return;
    }

    int idx = lb*256 + threadIdx.x;
    if (idx >= 16*HP_K*WP_K*12) return;
    int c8 = idx % 12;
    int p = idx / 12;
    int xo = p % WP_K;
    int yo = (p / WP_K) % HP_K;
    int bh = p / (WP_K*HP_K);
    const bf16* ip = in + (size_t)bh * 3200 * HD + c8*8;

    float acc[T0][8];
#pragma unroll
    for (int t = 0; t < T0; ++t)
#pragma unroll
        for (int j = 0; j < 8; ++j) acc[t][j] = 0.f;

#pragma unroll
    for (int dy = 0; dy < 3; ++dy) {
        int yi = 3*yo + dy - 1;
        if ((unsigned)yi >= (unsigned)NYC) continue;
#pragma unroll
        for (int dx = 0; dx < 3; ++dx) {
            int xi = 3*xo + dx - 1;
            if ((unsigned)xi >= (unsigned)NYC) continue;
            float wreg[3][8];
#pragma unroll
            for (int dt = 0; dt < 3; ++dt)
#pragma unroll
                for (int j = 0; j < 8; ++j)
                    wreg[dt][j] = lw[(dt*9 + dy*3 + dx)*HD + c8*8 + j];
            const bf16* colp = ip + ((size_t)(yi*NYC + xi))*HD;
#pragma unroll
            for (int t = 0; t < T0; ++t) {
                bf16x8 v = *(const bf16x8*)(colp + (size_t)t*400*HD);
                float f[8];
#pragma unroll
                for (int j = 0; j < 8; ++j) f[j] = (float)v[j];
#pragma unroll
                for (int dt = 0; dt < 3; ++dt) {
                    int to = t - dt + 1;
                    if (to < 0 || to >= T0) continue;
#pragma unroll
                    for (int j = 0; j < 8; ++j)
                        acc[to][j] += wreg[dt][j] * f[j];
                }
            }
        }
    }

#pragma unroll
    for (int to = 0; to < T0; ++to) {
        int l = (to*HP_K + yo)*WP_K + xo;
        if (seg == 1) {
#pragma unroll
            for (int j = 0; j < 8; ++j)
                vtout[((size_t)bh*HD + c8*8 + j)*LKP + l] = (bf16)acc[to][j];
        } else {
            bf16x8 ov;
#pragma unroll
            for (int j = 0; j < 8; ++j) ov[j] = (bf16)acc[to][j];
            *(bf16x8*)&kout[((size_t)bh*LKP + l)*HD + c8*8] = ov;
        }
    }
}

// ---------------- MFMA attention: block = (b,h) x 64 q rows, wave = 16 q rows -------
__global__ __launch_bounds__(256) void attn_mfma(
    const bf16* __restrict__ q, const bf16* __restrict__ k,
    const bf16* __restrict__ vt, bf16* __restrict__ out)
{
    const int tid = threadIdx.x;
    const int lane = tid & 63;
    const int w = tid >> 6;
    const int col = lane & 15;
    const int g = lane >> 4;
    const int blk = blockIdx.x;
    const int qblk = blk % (LQ/64);
    const int bh = blk / (LQ/64);
    const int q0 = qblk*64 + w*16;

    const bf16* Qp  = q  + ((size_t)bh*LQ + q0)*HD;
    const bf16* Kp  = k  + (size_t)bh*LKP*HD;
    const bf16* VTp = vt + (size_t)bh*HD*LKP;

    bf16x8 qf[3];
#pragma unroll
    for (int c = 0; c < 3; ++c)
        qf[c] = *(const bf16x8*)&Qp[(size_t)col*HD + c*32 + g*8];

    f32x4 o[6];
#pragma unroll
    for (int t = 0; t < 6; ++t) o[t] = (f32x4){0.f,0.f,0.f,0.f};
    float lsum = 0.f;

    for (int kc = 0; kc < LKP/32; ++kc) {
        const int kvb = kc*32;
        uint32_t P[2][2];
#pragma unroll
        for (int s = 0; s < 2; ++s) {
            f32x4 acc = (f32x4){0.f,0.f,0.f,0.f};
#pragma unroll
            for (int c = 0; c < 3; ++c) {
                bf16x8 kf = *(const bf16x8*)&Kp[(size_t)(kvb + s*16 + col)*HD + c*32 + g*8];
                acc = __builtin_amdgcn_mfma_f32_16x16x32_bf16(kf, qf[c], acc, 0, 0, 0);
            }
            bf16x4 pb;
#pragma unroll
            for (int r = 0; r < 4; ++r) {
                int kv = kvb + s*16 + g*4 + r;
                float p = (kv < LK) ? __expf(acc[r]*SCALE) : 0.f;
                lsum += p;
                pb[r] = (bf16)p;
            }
            union { bf16x4 v; uint32_t u[2]; } pk; pk.v = pb;
            P[s][0] = pk.u[0]; P[s][1] = pk.u[1];
        }
        uint32_t sa0 = (g < 2) ? P[1][0] : P[0][0];
        uint32_t sa1 = (g < 2) ? P[1][1] : P[0][1];
        uint32_t tb0 = (g < 2) ? P[0][0] : P[1][0];
        uint32_t tb1 = (g < 2) ? P[0][1] : P[1][1];
        uint32_t R32_0 = (uint32_t)__shfl_xor((int)sa0, 32);
        uint32_t R32_1 = (uint32_t)__shfl_xor((int)sa1, 32);
        uint32_t R48_0 = (uint32_t)__shfl_xor((int)sa0, 48);
        uint32_t R48_1 = (uint32_t)__shfl_xor((int)sa1, 48);
        uint32_t R16_0 = (uint32_t)__shfl_xor((int)tb0, 16);
        uint32_t R16_1 = (uint32_t)__shfl_xor((int)tb1, 16);
        union { uint32_t u[4]; bf16x8 v; } pf;
        pf.u[0] = (g == 0) ? P[0][0] : (g == 1) ? R48_0 : (g == 2) ? R32_0 : R16_0;
        pf.u[1] = (g == 0) ? P[0][1] : (g == 1) ? R48_1 : (g == 2) ? R32_1 : R16_1;
        pf.u[2] = (g == 0) ? R16_0 : (g == 1) ? R32_0 : (g == 2) ? R48_0 : P[1][0];
        pf.u[3] = (g == 0) ? R16_1 : (g == 1) ? R32_1 : (g == 2) ? R48_1 : P[1][1];
#pragma unroll
        for (int t = 0; t < 6; ++t) {
            bf16x8 vf = *(const bf16x8*)&VTp[(size_t)(t*16 + col)*LKP + kvb + g*8];
            o[t] = __builtin_amdgcn_mfma_f32_16x16x32_bf16(vf, pf.v, o[t], 0, 0, 0);
        }
    }

    lsum += __shfl_xor(lsum, 16);
    lsum += __shfl_xor(lsum, 32);
    float inv = 1.f / lsum;

    const int b = bh >> 3, nh = bh & 7;
    size_t obase = ((size_t)b*LQ + q0 + col)*CDIM + (size_t)nh*HD;
#pragma unroll
    for (int t = 0; t < 6; ++t) {
        bf16x4 qres = *(const bf16x4*)&Qp[(size_t)col*HD + t*16 + g*4];
        bf16x4 ov;
#pragma unroll
        for (int r = 0; r < 4; ++r)
            ov[r] = (bf16)(o[t][r]*inv + (float)qres[r]);
        *(bf16x4*)&out[obase + t*16 + g*4] = ov;
    }
}

extern "C" void kernel_launch(void* const* d_in, const int* in_sizes, int n_in,
                              void* d_out, int out_size, void* d_ws, size_t ws_size,
                              hipStream_t stream) {
    const float* x      = (const float*)d_in[0];
    const float* qkv_w  = (const float*)d_in[1];
    const float* qkv_b  = (const float*)d_in[2];
    const float* proj_w = (const float*)d_in[3];
    const float* proj_b = (const float*)d_in[4];
    const float* pq_w   = (const float*)d_in[5];
    const float* pk_w   = (const float*)d_in[6];
    const float* pv_w   = (const float*)d_in[7];

    uint8_t* ws = (uint8_t*)d_ws;
    bf16* x_bf     = (bf16*)(ws);                  // 77,070,336 B  [2][L0][768]
    bf16* qg_out   = (bf16*)(ws +  77070336);      // 77,070,336 B  [16][L0][96] (GELU'd Q)
    bf16* kv_c     = (bf16*)(ws + 154140672);      // 19,660,800 B  [2][16][3200][96]
    bf16* wqkv_bf  = (bf16*)(ws + 173801472);      // 3,538,944 B
    bf16* wproj_bf = (bf16*)(ws + 177340416);      // 1,179,648 B
    bf16* q_bf     = (bf16*)(ws + 178520064);      // 19,267,584 B  [16][6272][96]
    bf16* k_bf     = (bf16*)(ws + 197787648);      // 1,277,952 B   [16][416][96]
    bf16* vt_bf    = (bf16*)(ws + 199065600);      // 1,277,952 B   [16][96][416]
    bf16* attn_o   = (bf16*)(ws + 200343552);      // 19,267,584 B -> end 219,611,136

    cvt_all<<<2560, 256, 0, stream>>>((const f4*)x, (const f4*)qkv_w, (const f4*)proj_w,
                                      (bf16x4*)x_bf, (bf16x4*)wqkv_bf, (bf16x4*)wproj_bf);

    // merged Q + KV GEMM (2952 blocks, one dispatch, bf16 A via global_load_lds)
    gemm_qkv<<<NBQ + NBKV, 256, 0, stream>>>(x_bf, wqkv_bf, qkv_b, qg_out, kv_c);

    // merged convs (q + k + v + pad-zeroing, one dispatch)
    dwconv_all<<<668, 256, 0, stream>>>(qg_out, kv_c, pq_w, pk_w, pv_w,
                                        q_bf, k_bf, vt_bf);

    attn_mfma<<<16*(LQ/64), 256, 0, stream>>>(q_bf, k_bf, vt_bf, attn_o);

    gemm_proj<<<6*98, 256, 0, stream>>>(
        attn_o, wproj_bf, proj_b, (float*)d_out, 12544, 768, 768, 6);
}